// Round 4
// baseline (221.408 us; speedup 1.0000x reference)
//
#include <hip/hip_runtime.h>
#include <hip/hip_bf16.h>
#include <stdint.h>
#include <math.h>

// CausalMultiheadRoPEAttn: B=2, S=2048, D=1024, H=16, Dh=64
// prep (bf16 casts + rope table) -> fused QKV gemm (+bias+rope, V transposed,
// padded stride) -> flash attention: 256 blocks x 8 waves, KV-split flash
// decoding within block (perfect balance, 2 waves/SIMD), XCD-local heads
// -> out gemm.

typedef __bf16 bf16;
typedef __attribute__((ext_vector_type(4))) __bf16 bf16x4;
typedef __attribute__((ext_vector_type(8))) __bf16 bf16x8;
typedef __attribute__((ext_vector_type(4))) float f32x4;

#define SEQN 2048
#define DMOD 1024
#define NHEAD 16
#define DHEAD 64
#define MTOT 4096
#define VSTR 2080   // padded Vt row stride (elements)
// 0.125 * log2(e): scores land in log2 domain -> softmax uses exp2
#define QSCALE_LOG2E 0.18033688011112042f

__device__ __forceinline__ void gload_lds16(const bf16* g, bf16* l) {
  __builtin_amdgcn_global_load_lds(
      (const __attribute__((address_space(1))) uint32_t*)g,
      (__attribute__((address_space(3))) uint32_t*)l,
      16, 0, 0);
}

// ---------------------------------------------------------------- prep
__global__ __launch_bounds__(256) void prep_kernel(
    const float* __restrict__ X,
    const float* __restrict__ Wq, const float* __restrict__ Wk,
    const float* __restrict__ Wv, const float* __restrict__ Wo,
    bf16* __restrict__ Xb, bf16* __restrict__ Wqb, bf16* __restrict__ Wkb,
    bf16* __restrict__ Wvb, bf16* __restrict__ Wob,
    float* __restrict__ ctab, float* __restrict__ stab)
{
  const int tid = blockIdx.x * blockDim.x + threadIdx.x;
  const int nth = gridDim.x * blockDim.x;

  const float4* X4 = (const float4*)X;
  for (int i = tid; i < MTOT * DMOD / 4; i += nth) {
    float4 v = X4[i];
    bf16x4 o = { (bf16)v.x, (bf16)v.y, (bf16)v.z, (bf16)v.w };
    *(bf16x4*)(Xb + (size_t)i * 4) = o;
  }
  const float4* q4 = (const float4*)Wq;
  const float4* k4 = (const float4*)Wk;
  const float4* v4 = (const float4*)Wv;
  const float4* o4 = (const float4*)Wo;
  for (int i = tid; i < DMOD * DMOD / 4; i += nth) {
    float4 a = q4[i];
    float4 b = k4[i];
    float4 c = v4[i];
    float4 d = o4[i];
    *(bf16x4*)(Wqb + (size_t)i * 4) = bf16x4{ (bf16)a.x, (bf16)a.y, (bf16)a.z, (bf16)a.w };
    *(bf16x4*)(Wkb + (size_t)i * 4) = bf16x4{ (bf16)b.x, (bf16)b.y, (bf16)b.z, (bf16)b.w };
    *(bf16x4*)(Wvb + (size_t)i * 4) = bf16x4{ (bf16)c.x, (bf16)c.y, (bf16)c.z, (bf16)c.w };
    *(bf16x4*)(Wob + (size_t)i * 4) = bf16x4{ (bf16)d.x, (bf16)d.y, (bf16)d.z, (bf16)d.w };
  }
  for (int i = tid; i < SEQN * 32; i += nth) {
    const int s = i >> 5, p = i & 31;
    const float invf = (float)pow(10000.0, -(double)p / 32.0);
    const float ang = (float)s * invf;
    float sv, cv;
    sincosf(ang, &sv, &cv);
    ctab[i] = cv;
    stab[i] = sv;
  }
}

// ---------------------------------------------------------------- QKV gemm
__global__ __launch_bounds__(256) void gemm_qkv(
    const bf16* __restrict__ Xb,
    const bf16* __restrict__ Wqb, const bf16* __restrict__ Wkb, const bf16* __restrict__ Wvb,
    const float* __restrict__ bq, const float* __restrict__ bk, const float* __restrict__ bv,
    const float* __restrict__ ctab, const float* __restrict__ stab,
    bf16* __restrict__ Qb, bf16* __restrict__ Kb, bf16* __restrict__ Vtb)
{
  __shared__ bf16 sA[128 * 32];
  __shared__ bf16 sB[128 * 32];

  const int z = blockIdx.z;
  const bf16* Bm = (z == 0) ? Wqb : (z == 1) ? Wkb : Wvb;
  const float* bias = (z == 0) ? bq : (z == 1) ? bk : bv;

  const int t = threadIdx.x;
  const int lane = t & 63, l15 = lane & 15, g = lane >> 4;
  const int wave = t >> 6, wm = wave >> 1, wn = wave & 1;
  const int tileM = blockIdx.y * 128, tileN = blockIdx.x * 128;

  f32x4 acc[4][4] = {};

  const int srow = t >> 2, schk = t & 3;
  const bf16* gA = Xb + (size_t)(tileM + srow) * DMOD + schk * 8;
  const bf16* gB = Bm + (size_t)(tileN + srow) * DMOD + schk * 8;
  bf16* lA = sA + t * 8;
  bf16* lB = sB + t * 8;

  for (int k0 = 0; k0 < DMOD; k0 += 32) {
    __syncthreads();
    gload_lds16(gA + k0, lA);
    gload_lds16(gA + k0 + 64 * DMOD, lA + 2048);
    gload_lds16(gB + k0, lB);
    gload_lds16(gB + k0 + 64 * DMOD, lB + 2048);
    __syncthreads();
    bf16x8 af[4], bfr[4];
#pragma unroll
    for (int i = 0; i < 4; ++i)
      af[i] = *(const bf16x8*)(sA + (wm * 64 + i * 16 + l15) * 32 + g * 8);
#pragma unroll
    for (int j = 0; j < 4; ++j)
      bfr[j] = *(const bf16x8*)(sB + (wn * 64 + j * 16 + l15) * 32 + g * 8);
#pragma unroll
    for (int i = 0; i < 4; ++i)
#pragma unroll
      for (int j = 0; j < 4; ++j)
        acc[i][j] = __builtin_amdgcn_mfma_f32_16x16x32_bf16(af[i], bfr[j], acc[i][j], 0, 0, 0);
  }

#pragma unroll
  for (int j = 0; j < 4; ++j) {
    const int col = tileN + wn * 64 + j * 16 + l15;
    const float bcol = bias[col];
    const int h = col >> 6, d = col & 63;
#pragma unroll
    for (int i = 0; i < 4; ++i) {
#pragma unroll
      for (int r = 0; r < 4; ++r) {
        const int row = tileM + wm * 64 + i * 16 + g * 4 + r;
        const int b = row >> 11, s = row & (SEQN - 1);
        const float v = acc[i][j][r] + bcol;
        if (z != 2) {
          const int pair = d >> 1;
          const float cv = ctab[s * 32 + pair];
          const float sv = stab[s * 32 + pair];
          const float partner = __shfl_xor(v, 1);
          float rv = (d & 1) ? (partner * sv + v * cv) : (v * cv - partner * sv);
          if (z == 0) rv *= QSCALE_LOG2E;   // fold softmax scale+log2e into Q
          bf16* dst = (z == 0) ? Qb : Kb;
          dst[(((size_t)(b * NHEAD + h)) * SEQN + s) * DHEAD + d] = (bf16)rv;
        } else {
          Vtb[(((size_t)(b * NHEAD + h)) * DHEAD + d) * VSTR + s] = (bf16)v;
        }
      }
    }
  }
}

// ---------------------------------------------------------------- attention
// 256 blocks (8 qtile-pairs x 32 bh, bid%8==bh%8 for XCD L2 locality),
// 8 waves x 32 q-rows. Waves 0-3 and 4-7 cover the SAME 128 q-rows but split
// each phase's KV range in half (q+1 tiles each) -> every wave of every block
// does exactly 17 KV-iterations. Partials merged via LDS per phase.
__global__ __launch_bounds__(512, 2) void attn_kernel(
    const bf16* __restrict__ Qb, const bf16* __restrict__ Kb,
    const bf16* __restrict__ Vt, bf16* __restrict__ AO)
{
  __shared__ bf16 sP[8][2][16 * 68];
  __shared__ float sAcc[4][2][16][65];
  __shared__ float sM[4][2][16];
  __shared__ float sL[4][2][16];

  const int t = threadIdx.x;
  const int lane = t & 63, l15 = lane & 15, g = lane >> 4;
  const int wave = t >> 6;       // 0..7
  const int grp = wave >> 2;     // 0: lower KV half, 1: upper KV half
  const int wv = wave & 3;       // row-group / wave-pair id

  const int bid = blockIdx.x;
  const int pp = bid >> 5, bh = bid & 31;   // bid%8 == bh%8 -> XCD-local heads

  const bf16* Kp = Kb + (size_t)bh * SEQN * DHEAD;
  const bf16* Vp = Vt + (size_t)bh * DHEAD * VSTR;
  const bf16* Qp = Qb + (size_t)bh * SEQN * DHEAD;
  const int b = bh >> 4, h = bh & 15;

  auto prefetch = [&](bf16x8 (&K)[4][2], bf16x8 (&V)[4][2], int kv) {
#pragma unroll
    for (int j = 0; j < 4; ++j)
#pragma unroll
      for (int kc = 0; kc < 2; ++kc) {
        K[j][kc] = *(const bf16x8*)(Kp + (size_t)(kv + j * 16 + l15) * DHEAD + kc * 32 + g * 8);
        V[j][kc] = *(const bf16x8*)(Vp + (size_t)(j * 16 + l15) * VSTR + kv + kc * 32 + g * 8);
      }
  };

  auto run_phase = [&](int qtile) {
    const int q0 = qtile * 128;
    const int qbase = q0 + wv * 32;
    const int niter = qtile + 1;                 // 64-row KV tiles per group
    const int kvstart = grp ? 64 * niter : 0;

    bf16x8 aq[2][2];
#pragma unroll
    for (int qs = 0; qs < 2; ++qs)
#pragma unroll
      for (int kc = 0; kc < 2; ++kc)
        aq[qs][kc] = *(const bf16x8*)(Qp + (size_t)(qbase + qs * 16 + l15) * DHEAD + kc * 32 + g * 8);

    f32x4 acco[2][4] = {};
    float mrow[2][4], lrow[2][4];
#pragma unroll
    for (int qs = 0; qs < 2; ++qs)
#pragma unroll
      for (int r = 0; r < 4; ++r) { mrow[qs][r] = -1e30f; lrow[qs][r] = 0.f; }

    auto compute = [&](const bf16x8 (&K)[4][2], const bf16x8 (&V)[4][2], int kv0) {
      f32x4 sc[2][4] = {};
#pragma unroll
      for (int j = 0; j < 4; ++j)
#pragma unroll
        for (int kc = 0; kc < 2; ++kc)
#pragma unroll
          for (int qs = 0; qs < 2; ++qs)
            sc[qs][j] = __builtin_amdgcn_mfma_f32_16x16x32_bf16(aq[qs][kc], K[j][kc], sc[qs][j], 0, 0, 0);

#pragma unroll
      for (int qs = 0; qs < 2; ++qs) {
        const int qr = qbase + qs * 16;
        if (kv0 + 63 > qr) {   // tile touches/crosses the diagonal: mask
#pragma unroll
          for (int j = 0; j < 4; ++j) {
            const int kg = kv0 + j * 16 + l15;
#pragma unroll
            for (int r = 0; r < 4; ++r) {
              const int qg = qr + g * 4 + r;
              if (kg > qg) sc[qs][j][r] = -1e30f;
            }
          }
        }
        float pp_[4][4];
#pragma unroll
        for (int r = 0; r < 4; ++r) {
          float tm = fmaxf(fmaxf(sc[qs][0][r], sc[qs][1][r]), fmaxf(sc[qs][2][r], sc[qs][3][r]));
          tm = fmaxf(tm, __shfl_xor(tm, 1));
          tm = fmaxf(tm, __shfl_xor(tm, 2));
          tm = fmaxf(tm, __shfl_xor(tm, 4));
          tm = fmaxf(tm, __shfl_xor(tm, 8));
          const float mnew = fmaxf(mrow[qs][r], tm);
          const float alpha = __builtin_amdgcn_exp2f(mrow[qs][r] - mnew);
          mrow[qs][r] = mnew;
          float rs = 0.f;
#pragma unroll
          for (int j = 0; j < 4; ++j) {
            const float pv = __builtin_amdgcn_exp2f(sc[qs][j][r] - mnew);
            pp_[j][r] = pv;
            rs += pv;
          }
          rs += __shfl_xor(rs, 1);
          rs += __shfl_xor(rs, 2);
          rs += __shfl_xor(rs, 4);
          rs += __shfl_xor(rs, 8);
          lrow[qs][r] = lrow[qs][r] * alpha + rs;
#pragma unroll
          for (int j = 0; j < 4; ++j) acco[qs][j][r] *= alpha;
        }
#pragma unroll
        for (int r = 0; r < 4; ++r)
#pragma unroll
          for (int j = 0; j < 4; ++j)
            sP[wave][qs][(g * 4 + r) * 68 + j * 16 + l15] = (bf16)pp_[j][r];
      }

      asm volatile("s_waitcnt lgkmcnt(0)" ::: "memory");

      bf16x8 pa[2][2];
#pragma unroll
      for (int qs = 0; qs < 2; ++qs)
#pragma unroll
        for (int kc = 0; kc < 2; ++kc)
          pa[qs][kc] = *(const bf16x8*)(&sP[wave][qs][l15 * 68 + kc * 32 + g * 8]);

#pragma unroll
      for (int j = 0; j < 4; ++j)
#pragma unroll
        for (int kc = 0; kc < 2; ++kc)
#pragma unroll
          for (int qs = 0; qs < 2; ++qs)
            acco[qs][j] = __builtin_amdgcn_mfma_f32_16x16x32_bf16(pa[qs][kc], V[j][kc], acco[qs][j], 0, 0, 0);

      asm volatile("s_waitcnt lgkmcnt(0)" ::: "memory");
    };

    bf16x8 kA[4][2], vA[4][2], kB[4][2], vB[4][2];
    prefetch(kA, vA, kvstart);
    int it = 0;
    for (; it + 2 <= niter; it += 2) {
      prefetch(kB, vB, kvstart + (it + 1) * 64);
      compute(kA, vA, kvstart + it * 64);
      if (it + 3 <= niter) prefetch(kA, vA, kvstart + (it + 2) * 64);
      compute(kB, vB, kvstart + (it + 1) * 64);
    }
    if (it < niter) compute(kA, vA, kvstart + it * 64);

    // ---- merge the two KV-half partials (grp1 -> LDS, grp0 merges+stores)
    __syncthreads();
    if (grp == 1) {
#pragma unroll
      for (int qs = 0; qs < 2; ++qs) {
#pragma unroll
        for (int r = 0; r < 4; ++r) {
#pragma unroll
          for (int j = 0; j < 4; ++j)
            sAcc[wv][qs][g * 4 + r][j * 16 + l15] = acco[qs][j][r];
          if (l15 == 0) {
            sM[wv][qs][g * 4 + r] = mrow[qs][r];
            sL[wv][qs][g * 4 + r] = lrow[qs][r];
          }
        }
      }
    }
    __syncthreads();
    if (grp == 0) {
#pragma unroll
      for (int qs = 0; qs < 2; ++qs)
#pragma unroll
        for (int r = 0; r < 4; ++r) {
          const int row = g * 4 + r;
          const float mB = sM[wv][qs][row];
          const float lB = sL[wv][qs][row];
          const float ms = fmaxf(mrow[qs][r], mB);
          const float fA = __builtin_amdgcn_exp2f(mrow[qs][r] - ms);
          const float fB = __builtin_amdgcn_exp2f(mB - ms);
          const float linv = 1.f / (lrow[qs][r] * fA + lB * fB);
          const int q = qbase + qs * 16 + row;
#pragma unroll
          for (int j = 0; j < 4; ++j) {
            const float o = (acco[qs][j][r] * fA + sAcc[wv][qs][row][j * 16 + l15] * fB) * linv;
            AO[((size_t)(b * SEQN + q)) * DMOD + h * DHEAD + j * 16 + l15] = (bf16)o;
          }
        }
    }
  };

  run_phase(pp);
  run_phase(15 - pp);
}

// ---------------------------------------------------------------- out gemm
__global__ __launch_bounds__(256) void gemm_out(
    const bf16* __restrict__ AO, const bf16* __restrict__ Wob,
    const float* __restrict__ bo, float* __restrict__ out)
{
  __shared__ bf16 sA[128 * 32];
  __shared__ bf16 sB[128 * 32];

  const int t = threadIdx.x;
  const int lane = t & 63, l15 = lane & 15, g = lane >> 4;
  const int wave = t >> 6, wm = wave >> 1, wn = wave & 1;
  const int tileM = blockIdx.y * 128, tileN = blockIdx.x * 128;

  f32x4 acc[4][4] = {};

  const int srow = t >> 2, schk = t & 3;
  const bf16* gA = AO + (size_t)(tileM + srow) * DMOD + schk * 8;
  const bf16* gB = Wob + (size_t)(tileN + srow) * DMOD + schk * 8;
  bf16* lA = sA + t * 8;
  bf16* lB = sB + t * 8;

  for (int k0 = 0; k0 < DMOD; k0 += 32) {
    __syncthreads();
    gload_lds16(gA + k0, lA);
    gload_lds16(gA + k0 + 64 * DMOD, lA + 2048);
    gload_lds16(gB + k0, lB);
    gload_lds16(gB + k0 + 64 * DMOD, lB + 2048);
    __syncthreads();
    bf16x8 af[4], bfr[4];
#pragma unroll
    for (int i = 0; i < 4; ++i)
      af[i] = *(const bf16x8*)(sA + (wm * 64 + i * 16 + l15) * 32 + g * 8);
#pragma unroll
    for (int j = 0; j < 4; ++j)
      bfr[j] = *(const bf16x8*)(sB + (wn * 64 + j * 16 + l15) * 32 + g * 8);
#pragma unroll
    for (int i = 0; i < 4; ++i)
#pragma unroll
      for (int j = 0; j < 4; ++j)
        acc[i][j] = __builtin_amdgcn_mfma_f32_16x16x32_bf16(af[i], bfr[j], acc[i][j], 0, 0, 0);
  }

#pragma unroll
  for (int j = 0; j < 4; ++j) {
    const int col = tileN + wn * 64 + j * 16 + l15;
    const float bcol = bo[col];
#pragma unroll
    for (int i = 0; i < 4; ++i)
#pragma unroll
      for (int r = 0; r < 4; ++r) {
        const int row = tileM + wm * 64 + i * 16 + g * 4 + r;
        out[(size_t)row * DMOD + col] = acc[i][j][r] + bcol;
      }
  }
}

// ---------------------------------------------------------------- launch
extern "C" void kernel_launch(void* const* d_in, const int* in_sizes, int n_in,
                              void* d_out, int out_size, void* d_ws, size_t ws_size,
                              hipStream_t stream)
{
  (void)in_sizes; (void)n_in; (void)out_size; (void)ws_size;
  const float* X  = (const float*)d_in[0];
  const float* Wq = (const float*)d_in[1];
  const float* bq = (const float*)d_in[2];
  const float* Wk = (const float*)d_in[3];
  const float* bk = (const float*)d_in[4];
  const float* Wv = (const float*)d_in[5];
  const float* bv = (const float*)d_in[6];
  const float* Wo = (const float*)d_in[7];
  const float* bo = (const float*)d_in[8];

  char* ws = (char*)d_ws;
  float* ctab = (float*)(ws + 0);
  float* stab = (float*)(ws + 262144);
  bf16* Xb  = (bf16*)(ws + 524288);
  bf16* Wqb = (bf16*)(ws + 8912896);
  bf16* Wkb = (bf16*)(ws + 11010048);
  bf16* Wvb = (bf16*)(ws + 13107200);
  bf16* Wob = (bf16*)(ws + 15204352);
  bf16* Qb  = (bf16*)(ws + 17301504);
  bf16* Kb  = (bf16*)(ws + 25690112);
  bf16* Vtb = (bf16*)(ws + 34078720);   // 32*64*2080*2 = 8519680 bytes
  bf16* AO  = (bf16*)(ws + 42598400);

  prep_kernel<<<1024, 256, 0, stream>>>(X, Wq, Wk, Wv, Wo, Xb, Wqb, Wkb, Wvb, Wob, ctab, stab);
  gemm_qkv<<<dim3(8, 32, 3), 256, 0, stream>>>(Xb, Wqb, Wkb, Wvb, bq, bk, bv, ctab, stab, Qb, Kb, Vtb);
  attn_kernel<<<256, 512, 0, stream>>>(Qb, Kb, Vtb, AO);
  gemm_out<<<dim3(8, 32), 256, 0, stream>>>(AO, Wob, bo, (float*)d_out);
}

// Round 5
// 206.595 us; speedup vs baseline: 1.0717x; 1.0717x over previous
//
#include <hip/hip_runtime.h>
#include <hip/hip_bf16.h>
#include <stdint.h>
#include <math.h>

// CausalMultiheadRoPEAttn: B=2, S=2048, D=1024, H=16, Dh=64
// prep (bf16 casts + rope table) -> fused QKV gemm (+bias+rope, V transposed,
// padded stride) -> flash attention: QBLK=64, 512 blocks (2/CU), 4 waves x
// 16 q-rows, register double-buffered K/V, perfectly balanced qtile pairs
// -> out gemm.

typedef __bf16 bf16;
typedef __attribute__((ext_vector_type(4))) __bf16 bf16x4;
typedef __attribute__((ext_vector_type(8))) __bf16 bf16x8;
typedef __attribute__((ext_vector_type(4))) float f32x4;

#define SEQN 2048
#define DMOD 1024
#define NHEAD 16
#define DHEAD 64
#define MTOT 4096
#define VSTR 2080   // padded Vt row stride (elements)
// 0.125 * log2(e): scores land in log2 domain -> softmax uses exp2
#define QSCALE_LOG2E 0.18033688011112042f

__device__ __forceinline__ void gload_lds16(const bf16* g, bf16* l) {
  __builtin_amdgcn_global_load_lds(
      (const __attribute__((address_space(1))) uint32_t*)g,
      (__attribute__((address_space(3))) uint32_t*)l,
      16, 0, 0);
}

// ---------------------------------------------------------------- prep
__global__ __launch_bounds__(256) void prep_kernel(
    const float* __restrict__ X,
    const float* __restrict__ Wq, const float* __restrict__ Wk,
    const float* __restrict__ Wv, const float* __restrict__ Wo,
    bf16* __restrict__ Xb, bf16* __restrict__ Wqb, bf16* __restrict__ Wkb,
    bf16* __restrict__ Wvb, bf16* __restrict__ Wob,
    float* __restrict__ ctab, float* __restrict__ stab)
{
  const int tid = blockIdx.x * blockDim.x + threadIdx.x;
  const int nth = gridDim.x * blockDim.x;

  const float4* X4 = (const float4*)X;
  for (int i = tid; i < MTOT * DMOD / 4; i += nth) {
    float4 v = X4[i];
    bf16x4 o = { (bf16)v.x, (bf16)v.y, (bf16)v.z, (bf16)v.w };
    *(bf16x4*)(Xb + (size_t)i * 4) = o;
  }
  const float4* q4 = (const float4*)Wq;
  const float4* k4 = (const float4*)Wk;
  const float4* v4 = (const float4*)Wv;
  const float4* o4 = (const float4*)Wo;
  for (int i = tid; i < DMOD * DMOD / 4; i += nth) {
    float4 a = q4[i];
    float4 b = k4[i];
    float4 c = v4[i];
    float4 d = o4[i];
    *(bf16x4*)(Wqb + (size_t)i * 4) = bf16x4{ (bf16)a.x, (bf16)a.y, (bf16)a.z, (bf16)a.w };
    *(bf16x4*)(Wkb + (size_t)i * 4) = bf16x4{ (bf16)b.x, (bf16)b.y, (bf16)b.z, (bf16)b.w };
    *(bf16x4*)(Wvb + (size_t)i * 4) = bf16x4{ (bf16)c.x, (bf16)c.y, (bf16)c.z, (bf16)c.w };
    *(bf16x4*)(Wob + (size_t)i * 4) = bf16x4{ (bf16)d.x, (bf16)d.y, (bf16)d.z, (bf16)d.w };
  }
  for (int i = tid; i < SEQN * 32; i += nth) {
    const int s = i >> 5, p = i & 31;
    const float invf = (float)pow(10000.0, -(double)p / 32.0);
    const float ang = (float)s * invf;
    float sv, cv;
    sincosf(ang, &sv, &cv);
    ctab[i] = cv;
    stab[i] = sv;
  }
}

// ---------------------------------------------------------------- QKV gemm
__global__ __launch_bounds__(256) void gemm_qkv(
    const bf16* __restrict__ Xb,
    const bf16* __restrict__ Wqb, const bf16* __restrict__ Wkb, const bf16* __restrict__ Wvb,
    const float* __restrict__ bq, const float* __restrict__ bk, const float* __restrict__ bv,
    const float* __restrict__ ctab, const float* __restrict__ stab,
    bf16* __restrict__ Qb, bf16* __restrict__ Kb, bf16* __restrict__ Vtb)
{
  __shared__ bf16 sA[128 * 32];
  __shared__ bf16 sB[128 * 32];

  const int z = blockIdx.z;
  const bf16* Bm = (z == 0) ? Wqb : (z == 1) ? Wkb : Wvb;
  const float* bias = (z == 0) ? bq : (z == 1) ? bk : bv;

  const int t = threadIdx.x;
  const int lane = t & 63, l15 = lane & 15, g = lane >> 4;
  const int wave = t >> 6, wm = wave >> 1, wn = wave & 1;
  const int tileM = blockIdx.y * 128, tileN = blockIdx.x * 128;

  f32x4 acc[4][4] = {};

  const int srow = t >> 2, schk = t & 3;
  const bf16* gA = Xb + (size_t)(tileM + srow) * DMOD + schk * 8;
  const bf16* gB = Bm + (size_t)(tileN + srow) * DMOD + schk * 8;
  bf16* lA = sA + t * 8;
  bf16* lB = sB + t * 8;

  for (int k0 = 0; k0 < DMOD; k0 += 32) {
    __syncthreads();
    gload_lds16(gA + k0, lA);
    gload_lds16(gA + k0 + 64 * DMOD, lA + 2048);
    gload_lds16(gB + k0, lB);
    gload_lds16(gB + k0 + 64 * DMOD, lB + 2048);
    __syncthreads();
    bf16x8 af[4], bfr[4];
#pragma unroll
    for (int i = 0; i < 4; ++i)
      af[i] = *(const bf16x8*)(sA + (wm * 64 + i * 16 + l15) * 32 + g * 8);
#pragma unroll
    for (int j = 0; j < 4; ++j)
      bfr[j] = *(const bf16x8*)(sB + (wn * 64 + j * 16 + l15) * 32 + g * 8);
#pragma unroll
    for (int i = 0; i < 4; ++i)
#pragma unroll
      for (int j = 0; j < 4; ++j)
        acc[i][j] = __builtin_amdgcn_mfma_f32_16x16x32_bf16(af[i], bfr[j], acc[i][j], 0, 0, 0);
  }

#pragma unroll
  for (int j = 0; j < 4; ++j) {
    const int col = tileN + wn * 64 + j * 16 + l15;
    const float bcol = bias[col];
    const int h = col >> 6, d = col & 63;
#pragma unroll
    for (int i = 0; i < 4; ++i) {
#pragma unroll
      for (int r = 0; r < 4; ++r) {
        const int row = tileM + wm * 64 + i * 16 + g * 4 + r;
        const int b = row >> 11, s = row & (SEQN - 1);
        const float v = acc[i][j][r] + bcol;
        if (z != 2) {
          const int pair = d >> 1;
          const float cv = ctab[s * 32 + pair];
          const float sv = stab[s * 32 + pair];
          const float partner = __shfl_xor(v, 1);
          float rv = (d & 1) ? (partner * sv + v * cv) : (v * cv - partner * sv);
          if (z == 0) rv *= QSCALE_LOG2E;   // fold softmax scale+log2e into Q
          bf16* dst = (z == 0) ? Qb : Kb;
          dst[(((size_t)(b * NHEAD + h)) * SEQN + s) * DHEAD + d] = (bf16)rv;
        } else {
          Vtb[(((size_t)(b * NHEAD + h)) * DHEAD + d) * VSTR + s] = (bf16)v;
        }
      }
    }
  }
}

// ---------------------------------------------------------------- attention
// 512 blocks (16 qtile-pairs x 32 bh; bid%8==bh%8 -> XCD-local heads),
// 2 blocks/CU. 4 waves x 16 q-rows (QBLK=64). Pair p with 31-p: every block
// does exactly 33 KV-iterations. Register double-buffered K/V, no barriers.
__global__ __launch_bounds__(256, 2) void attn_kernel(
    const bf16* __restrict__ Qb, const bf16* __restrict__ Kb,
    const bf16* __restrict__ Vt, bf16* __restrict__ AO)
{
  __shared__ bf16 sP[4][16 * 68];

  const int t = threadIdx.x;
  const int lane = t & 63, l15 = lane & 15, g = lane >> 4;
  const int wave = t >> 6;

  const int bid = blockIdx.x;
  const int p = bid >> 5, bh = bid & 31;   // bid%8 == bh%8

  const bf16* Kp = Kb + (size_t)bh * SEQN * DHEAD;
  const bf16* Vp = Vt + (size_t)bh * DHEAD * VSTR;
  const bf16* Qp = Qb + (size_t)bh * SEQN * DHEAD;
  const int b = bh >> 4, h = bh & 15;

  auto prefetch = [&](bf16x8 (&K)[4][2], bf16x8 (&V)[4][2], int kv) {
#pragma unroll
    for (int j = 0; j < 4; ++j)
#pragma unroll
      for (int kc = 0; kc < 2; ++kc) {
        K[j][kc] = *(const bf16x8*)(Kp + (size_t)(kv + j * 16 + l15) * DHEAD + kc * 32 + g * 8);
        V[j][kc] = *(const bf16x8*)(Vp + (size_t)(j * 16 + l15) * VSTR + kv + kc * 32 + g * 8);
      }
  };

  auto run_phase = [&](int qtile) {
    const int q0 = qtile * 64;
    const int qbase = q0 + wave * 16;
    const int niter = qtile + 1;   // 64-row KV tiles

    bf16x8 aq[2];
#pragma unroll
    for (int kc = 0; kc < 2; ++kc)
      aq[kc] = *(const bf16x8*)(Qp + (size_t)(qbase + l15) * DHEAD + kc * 32 + g * 8);

    f32x4 acco[4] = {};
    float mrow[4], lrow[4];
#pragma unroll
    for (int r = 0; r < 4; ++r) { mrow[r] = -1e30f; lrow[r] = 0.f; }

    auto compute = [&](const bf16x8 (&K)[4][2], const bf16x8 (&V)[4][2], int kv0) {
      f32x4 sc[4] = {};
#pragma unroll
      for (int j = 0; j < 4; ++j)
#pragma unroll
        for (int kc = 0; kc < 2; ++kc)
          sc[j] = __builtin_amdgcn_mfma_f32_16x16x32_bf16(aq[kc], K[j][kc], sc[j], 0, 0, 0);

      if (kv0 + 63 > qbase) {   // tile touches/crosses the diagonal: mask
#pragma unroll
        for (int j = 0; j < 4; ++j) {
          const int kg = kv0 + j * 16 + l15;
#pragma unroll
          for (int r = 0; r < 4; ++r) {
            const int qg = qbase + g * 4 + r;
            if (kg > qg) sc[j][r] = -1e30f;
          }
        }
      }
      float pp[4][4];
#pragma unroll
      for (int r = 0; r < 4; ++r) {
        float tm = fmaxf(fmaxf(sc[0][r], sc[1][r]), fmaxf(sc[2][r], sc[3][r]));
        tm = fmaxf(tm, __shfl_xor(tm, 1));
        tm = fmaxf(tm, __shfl_xor(tm, 2));
        tm = fmaxf(tm, __shfl_xor(tm, 4));
        tm = fmaxf(tm, __shfl_xor(tm, 8));
        const float mnew = fmaxf(mrow[r], tm);
        const float alpha = __builtin_amdgcn_exp2f(mrow[r] - mnew);
        mrow[r] = mnew;
        float rs = 0.f;
#pragma unroll
        for (int j = 0; j < 4; ++j) {
          const float pv = __builtin_amdgcn_exp2f(sc[j][r] - mnew);
          pp[j][r] = pv;
          rs += pv;
        }
        rs += __shfl_xor(rs, 1);
        rs += __shfl_xor(rs, 2);
        rs += __shfl_xor(rs, 4);
        rs += __shfl_xor(rs, 8);
        lrow[r] = lrow[r] * alpha + rs;
#pragma unroll
        for (int j = 0; j < 4; ++j) acco[j][r] *= alpha;
      }
#pragma unroll
      for (int r = 0; r < 4; ++r)
#pragma unroll
        for (int j = 0; j < 4; ++j)
          sP[wave][(g * 4 + r) * 68 + j * 16 + l15] = (bf16)pp[j][r];

      asm volatile("s_waitcnt lgkmcnt(0)" ::: "memory");

      bf16x8 pa[2];
#pragma unroll
      for (int kc = 0; kc < 2; ++kc)
        pa[kc] = *(const bf16x8*)(&sP[wave][l15 * 68 + kc * 32 + g * 8]);

#pragma unroll
      for (int j = 0; j < 4; ++j)
#pragma unroll
        for (int kc = 0; kc < 2; ++kc)
          acco[j] = __builtin_amdgcn_mfma_f32_16x16x32_bf16(pa[kc], V[j][kc], acco[j], 0, 0, 0);

      asm volatile("s_waitcnt lgkmcnt(0)" ::: "memory");
    };

    bf16x8 kA[4][2], vA[4][2], kB[4][2], vB[4][2];
    prefetch(kA, vA, 0);
    int it = 0;
    for (; it + 1 < niter; it += 2) {
      prefetch(kB, vB, (it + 1) * 64);
      compute(kA, vA, it * 64);
      if (it + 2 < niter) prefetch(kA, vA, (it + 2) * 64);
      compute(kB, vB, (it + 1) * 64);
    }
    if (it < niter) compute(kA, vA, it * 64);

    // epilogue
#pragma unroll
    for (int j = 0; j < 4; ++j)
#pragma unroll
      for (int r = 0; r < 4; ++r) {
        const int q = qbase + g * 4 + r;
        const int dd = j * 16 + l15;
        const float v = acco[j][r] / lrow[r];
        AO[((size_t)(b * SEQN + q)) * DMOD + h * DHEAD + dd] = (bf16)v;
      }
  };

  run_phase(p);
  run_phase(31 - p);
}

// ---------------------------------------------------------------- out gemm
__global__ __launch_bounds__(256) void gemm_out(
    const bf16* __restrict__ AO, const bf16* __restrict__ Wob,
    const float* __restrict__ bo, float* __restrict__ out)
{
  __shared__ bf16 sA[128 * 32];
  __shared__ bf16 sB[128 * 32];

  const int t = threadIdx.x;
  const int lane = t & 63, l15 = lane & 15, g = lane >> 4;
  const int wave = t >> 6, wm = wave >> 1, wn = wave & 1;
  const int tileM = blockIdx.y * 128, tileN = blockIdx.x * 128;

  f32x4 acc[4][4] = {};

  const int srow = t >> 2, schk = t & 3;
  const bf16* gA = AO + (size_t)(tileM + srow) * DMOD + schk * 8;
  const bf16* gB = Wob + (size_t)(tileN + srow) * DMOD + schk * 8;
  bf16* lA = sA + t * 8;
  bf16* lB = sB + t * 8;

  for (int k0 = 0; k0 < DMOD; k0 += 32) {
    __syncthreads();
    gload_lds16(gA + k0, lA);
    gload_lds16(gA + k0 + 64 * DMOD, lA + 2048);
    gload_lds16(gB + k0, lB);
    gload_lds16(gB + k0 + 64 * DMOD, lB + 2048);
    __syncthreads();
    bf16x8 af[4], bfr[4];
#pragma unroll
    for (int i = 0; i < 4; ++i)
      af[i] = *(const bf16x8*)(sA + (wm * 64 + i * 16 + l15) * 32 + g * 8);
#pragma unroll
    for (int j = 0; j < 4; ++j)
      bfr[j] = *(const bf16x8*)(sB + (wn * 64 + j * 16 + l15) * 32 + g * 8);
#pragma unroll
    for (int i = 0; i < 4; ++i)
#pragma unroll
      for (int j = 0; j < 4; ++j)
        acc[i][j] = __builtin_amdgcn_mfma_f32_16x16x32_bf16(af[i], bfr[j], acc[i][j], 0, 0, 0);
  }

#pragma unroll
  for (int j = 0; j < 4; ++j) {
    const int col = tileN + wn * 64 + j * 16 + l15;
    const float bcol = bo[col];
#pragma unroll
    for (int i = 0; i < 4; ++i)
#pragma unroll
      for (int r = 0; r < 4; ++r) {
        const int row = tileM + wm * 64 + i * 16 + g * 4 + r;
        out[(size_t)row * DMOD + col] = acc[i][j][r] + bcol;
      }
  }
}

// ---------------------------------------------------------------- launch
extern "C" void kernel_launch(void* const* d_in, const int* in_sizes, int n_in,
                              void* d_out, int out_size, void* d_ws, size_t ws_size,
                              hipStream_t stream)
{
  (void)in_sizes; (void)n_in; (void)out_size; (void)ws_size;
  const float* X  = (const float*)d_in[0];
  const float* Wq = (const float*)d_in[1];
  const float* bq = (const float*)d_in[2];
  const float* Wk = (const float*)d_in[3];
  const float* bk = (const float*)d_in[4];
  const float* Wv = (const float*)d_in[5];
  const float* bv = (const float*)d_in[6];
  const float* Wo = (const float*)d_in[7];
  const float* bo = (const float*)d_in[8];

  char* ws = (char*)d_ws;
  float* ctab = (float*)(ws + 0);
  float* stab = (float*)(ws + 262144);
  bf16* Xb  = (bf16*)(ws + 524288);
  bf16* Wqb = (bf16*)(ws + 8912896);
  bf16* Wkb = (bf16*)(ws + 11010048);
  bf16* Wvb = (bf16*)(ws + 13107200);
  bf16* Wob = (bf16*)(ws + 15204352);
  bf16* Qb  = (bf16*)(ws + 17301504);
  bf16* Kb  = (bf16*)(ws + 25690112);
  bf16* Vtb = (bf16*)(ws + 34078720);   // 32*64*2080*2 = 8519680 bytes
  bf16* AO  = (bf16*)(ws + 42598400);

  prep_kernel<<<1024, 256, 0, stream>>>(X, Wq, Wk, Wv, Wo, Xb, Wqb, Wkb, Wvb, Wob, ctab, stab);
  gemm_qkv<<<dim3(8, 32, 3), 256, 0, stream>>>(Xb, Wqb, Wkb, Wvb, bq, bk, bv, ctab, stab, Qb, Kb, Vtb);
  attn_kernel<<<512, 256, 0, stream>>>(Qb, Kb, Vtb, AO);
  gemm_out<<<dim3(8, 32), 256, 0, stream>>>(AO, Wob, bo, (float*)d_out);
}

// Round 6
// 206.245 us; speedup vs baseline: 1.0735x; 1.0017x over previous
//
#include <hip/hip_runtime.h>
#include <hip/hip_bf16.h>
#include <stdint.h>
#include <math.h>

// CausalMultiheadRoPEAttn: B=2, S=2048, D=1024, H=16, Dh=64
// prep (bf16 casts + rope table) -> fused QKV gemm (+bias+rope, V transposed,
// padded stride) -> flash attention: QBLK=64, 512 blocks (2/CU), 4 waves x
// 16 q-rows, register double-buffered K/V, perfectly balanced qtile pairs
// -> out gemm.

typedef __bf16 bf16;
typedef __attribute__((ext_vector_type(4))) __bf16 bf16x4;
typedef __attribute__((ext_vector_type(8))) __bf16 bf16x8;
typedef __attribute__((ext_vector_type(4))) float f32x4;

#define SEQN 2048
#define DMOD 1024
#define NHEAD 16
#define DHEAD 64
#define MTOT 4096
#define VSTR 2080   // padded Vt row stride (elements)
// 0.125 * log2(e): scores land in log2 domain -> softmax uses exp2
#define QSCALE_LOG2E 0.18033688011112042f

__device__ __forceinline__ void gload_lds16(const bf16* g, bf16* l) {
  __builtin_amdgcn_global_load_lds(
      (const __attribute__((address_space(1))) uint32_t*)g,
      (__attribute__((address_space(3))) uint32_t*)l,
      16, 0, 0);
}

// ---------------------------------------------------------------- prep
__global__ __launch_bounds__(256) void prep_kernel(
    const float* __restrict__ X,
    const float* __restrict__ Wq, const float* __restrict__ Wk,
    const float* __restrict__ Wv, const float* __restrict__ Wo,
    bf16* __restrict__ Xb, bf16* __restrict__ Wqb, bf16* __restrict__ Wkb,
    bf16* __restrict__ Wvb, bf16* __restrict__ Wob,
    float* __restrict__ ctab, float* __restrict__ stab)
{
  const int tid = blockIdx.x * blockDim.x + threadIdx.x;
  const int nth = gridDim.x * blockDim.x;

  const float4* X4 = (const float4*)X;
  for (int i = tid; i < MTOT * DMOD / 4; i += nth) {
    float4 v = X4[i];
    bf16x4 o = { (bf16)v.x, (bf16)v.y, (bf16)v.z, (bf16)v.w };
    *(bf16x4*)(Xb + (size_t)i * 4) = o;
  }
  const float4* q4 = (const float4*)Wq;
  const float4* k4 = (const float4*)Wk;
  const float4* v4 = (const float4*)Wv;
  const float4* o4 = (const float4*)Wo;
  for (int i = tid; i < DMOD * DMOD / 4; i += nth) {
    float4 a = q4[i];
    float4 b = k4[i];
    float4 c = v4[i];
    float4 d = o4[i];
    *(bf16x4*)(Wqb + (size_t)i * 4) = bf16x4{ (bf16)a.x, (bf16)a.y, (bf16)a.z, (bf16)a.w };
    *(bf16x4*)(Wkb + (size_t)i * 4) = bf16x4{ (bf16)b.x, (bf16)b.y, (bf16)b.z, (bf16)b.w };
    *(bf16x4*)(Wvb + (size_t)i * 4) = bf16x4{ (bf16)c.x, (bf16)c.y, (bf16)c.z, (bf16)c.w };
    *(bf16x4*)(Wob + (size_t)i * 4) = bf16x4{ (bf16)d.x, (bf16)d.y, (bf16)d.z, (bf16)d.w };
  }
  for (int i = tid; i < SEQN * 32; i += nth) {
    const int s = i >> 5, p = i & 31;
    const float invf = (float)pow(10000.0, -(double)p / 32.0);
    const float ang = (float)s * invf;
    float sv, cv;
    sincosf(ang, &sv, &cv);
    ctab[i] = cv;
    stab[i] = sv;
  }
}

// ---------------------------------------------------------------- QKV gemm
__global__ __launch_bounds__(256) void gemm_qkv(
    const bf16* __restrict__ Xb,
    const bf16* __restrict__ Wqb, const bf16* __restrict__ Wkb, const bf16* __restrict__ Wvb,
    const float* __restrict__ bq, const float* __restrict__ bk, const float* __restrict__ bv,
    const float* __restrict__ ctab, const float* __restrict__ stab,
    bf16* __restrict__ Qb, bf16* __restrict__ Kb, bf16* __restrict__ Vtb)
{
  __shared__ bf16 sA[128 * 32];
  __shared__ bf16 sB[128 * 32];

  const int z = blockIdx.z;
  const bf16* Bm = (z == 0) ? Wqb : (z == 1) ? Wkb : Wvb;
  const float* bias = (z == 0) ? bq : (z == 1) ? bk : bv;

  const int t = threadIdx.x;
  const int lane = t & 63, l15 = lane & 15, g = lane >> 4;
  const int wave = t >> 6, wm = wave >> 1, wn = wave & 1;
  const int tileM = blockIdx.y * 128, tileN = blockIdx.x * 128;

  f32x4 acc[4][4] = {};

  const int srow = t >> 2, schk = t & 3;
  const bf16* gA = Xb + (size_t)(tileM + srow) * DMOD + schk * 8;
  const bf16* gB = Bm + (size_t)(tileN + srow) * DMOD + schk * 8;
  bf16* lA = sA + t * 8;
  bf16* lB = sB + t * 8;

  for (int k0 = 0; k0 < DMOD; k0 += 32) {
    __syncthreads();
    gload_lds16(gA + k0, lA);
    gload_lds16(gA + k0 + 64 * DMOD, lA + 2048);
    gload_lds16(gB + k0, lB);
    gload_lds16(gB + k0 + 64 * DMOD, lB + 2048);
    __syncthreads();
    bf16x8 af[4], bfr[4];
#pragma unroll
    for (int i = 0; i < 4; ++i)
      af[i] = *(const bf16x8*)(sA + (wm * 64 + i * 16 + l15) * 32 + g * 8);
#pragma unroll
    for (int j = 0; j < 4; ++j)
      bfr[j] = *(const bf16x8*)(sB + (wn * 64 + j * 16 + l15) * 32 + g * 8);
#pragma unroll
    for (int i = 0; i < 4; ++i)
#pragma unroll
      for (int j = 0; j < 4; ++j)
        acc[i][j] = __builtin_amdgcn_mfma_f32_16x16x32_bf16(af[i], bfr[j], acc[i][j], 0, 0, 0);
  }

#pragma unroll
  for (int j = 0; j < 4; ++j) {
    const int col = tileN + wn * 64 + j * 16 + l15;
    const float bcol = bias[col];
    const int h = col >> 6, d = col & 63;
#pragma unroll
    for (int i = 0; i < 4; ++i) {
#pragma unroll
      for (int r = 0; r < 4; ++r) {
        const int row = tileM + wm * 64 + i * 16 + g * 4 + r;
        const int b = row >> 11, s = row & (SEQN - 1);
        const float v = acc[i][j][r] + bcol;
        if (z != 2) {
          const int pair = d >> 1;
          const float cv = ctab[s * 32 + pair];
          const float sv = stab[s * 32 + pair];
          const float partner = __shfl_xor(v, 1);
          float rv = (d & 1) ? (partner * sv + v * cv) : (v * cv - partner * sv);
          if (z == 0) rv *= QSCALE_LOG2E;   // fold softmax scale+log2e into Q
          bf16* dst = (z == 0) ? Qb : Kb;
          dst[(((size_t)(b * NHEAD + h)) * SEQN + s) * DHEAD + d] = (bf16)rv;
        } else {
          Vtb[(((size_t)(b * NHEAD + h)) * DHEAD + d) * VSTR + s] = (bf16)v;
        }
      }
    }
  }
}

// ---------------------------------------------------------------- attention
// 512 blocks (16 qtile-pairs x 32 bh; bid%8==bh%8 -> XCD-local heads),
// 2 blocks/CU. 4 waves x 16 q-rows (QBLK=64). Pair p with 31-p: every block
// does exactly 33 KV-iterations. Register double-buffered K/V, no barriers.
__global__ __launch_bounds__(256, 2) void attn_kernel(
    const bf16* __restrict__ Qb, const bf16* __restrict__ Kb,
    const bf16* __restrict__ Vt, bf16* __restrict__ AO)
{
  __shared__ bf16 sP[4][16 * 68];

  const int t = threadIdx.x;
  const int lane = t & 63, l15 = lane & 15, g = lane >> 4;
  const int wave = t >> 6;

  const int bid = blockIdx.x;
  const int p = bid >> 5, bh = bid & 31;   // bid%8 == bh%8

  const bf16* Kp = Kb + (size_t)bh * SEQN * DHEAD;
  const bf16* Vp = Vt + (size_t)bh * DHEAD * VSTR;
  const bf16* Qp = Qb + (size_t)bh * SEQN * DHEAD;
  const int b = bh >> 4, h = bh & 15;

  auto prefetch = [&](bf16x8 (&K)[4][2], bf16x8 (&V)[4][2], int kv) {
#pragma unroll
    for (int j = 0; j < 4; ++j)
#pragma unroll
      for (int kc = 0; kc < 2; ++kc) {
        K[j][kc] = *(const bf16x8*)(Kp + (size_t)(kv + j * 16 + l15) * DHEAD + kc * 32 + g * 8);
        V[j][kc] = *(const bf16x8*)(Vp + (size_t)(j * 16 + l15) * VSTR + kv + kc * 32 + g * 8);
      }
  };

  auto run_phase = [&](int qtile) {
    const int q0 = qtile * 64;
    const int qbase = q0 + wave * 16;
    const int niter = qtile + 1;   // 64-row KV tiles

    bf16x8 aq[2];
#pragma unroll
    for (int kc = 0; kc < 2; ++kc)
      aq[kc] = *(const bf16x8*)(Qp + (size_t)(qbase + l15) * DHEAD + kc * 32 + g * 8);

    f32x4 acco[4] = {};
    float mrow[4], lrow[4];
#pragma unroll
    for (int r = 0; r < 4; ++r) { mrow[r] = -1e30f; lrow[r] = 0.f; }

    auto compute = [&](const bf16x8 (&K)[4][2], const bf16x8 (&V)[4][2], int kv0) {
      f32x4 sc[4] = {};
#pragma unroll
      for (int j = 0; j < 4; ++j)
#pragma unroll
        for (int kc = 0; kc < 2; ++kc)
          sc[j] = __builtin_amdgcn_mfma_f32_16x16x32_bf16(aq[kc], K[j][kc], sc[j], 0, 0, 0);

      if (kv0 + 63 > qbase) {   // tile touches/crosses the diagonal: mask
#pragma unroll
        for (int j = 0; j < 4; ++j) {
          const int kg = kv0 + j * 16 + l15;
#pragma unroll
          for (int r = 0; r < 4; ++r) {
            const int qg = qbase + g * 4 + r;
            if (kg > qg) sc[j][r] = -1e30f;
          }
        }
      }
      float pp[4][4];
#pragma unroll
      for (int r = 0; r < 4; ++r) {
        float tm = fmaxf(fmaxf(sc[0][r], sc[1][r]), fmaxf(sc[2][r], sc[3][r]));
        tm = fmaxf(tm, __shfl_xor(tm, 1));
        tm = fmaxf(tm, __shfl_xor(tm, 2));
        tm = fmaxf(tm, __shfl_xor(tm, 4));
        tm = fmaxf(tm, __shfl_xor(tm, 8));
        const float mnew = fmaxf(mrow[r], tm);
        const float alpha = __builtin_amdgcn_exp2f(mrow[r] - mnew);
        mrow[r] = mnew;
        float rs = 0.f;
#pragma unroll
        for (int j = 0; j < 4; ++j) {
          const float pv = __builtin_amdgcn_exp2f(sc[j][r] - mnew);
          pp[j][r] = pv;
          rs += pv;
        }
        rs += __shfl_xor(rs, 1);
        rs += __shfl_xor(rs, 2);
        rs += __shfl_xor(rs, 4);
        rs += __shfl_xor(rs, 8);
        lrow[r] = lrow[r] * alpha + rs;
#pragma unroll
        for (int j = 0; j < 4; ++j) acco[j][r] *= alpha;
      }
#pragma unroll
      for (int r = 0; r < 4; ++r)
#pragma unroll
        for (int j = 0; j < 4; ++j)
          sP[wave][(g * 4 + r) * 68 + j * 16 + l15] = (bf16)pp[j][r];

      asm volatile("s_waitcnt lgkmcnt(0)" ::: "memory");

      bf16x8 pa[2];
#pragma unroll
      for (int kc = 0; kc < 2; ++kc)
        pa[kc] = *(const bf16x8*)(&sP[wave][l15 * 68 + kc * 32 + g * 8]);

#pragma unroll
      for (int j = 0; j < 4; ++j)
#pragma unroll
        for (int kc = 0; kc < 2; ++kc)
          acco[j] = __builtin_amdgcn_mfma_f32_16x16x32_bf16(pa[kc], V[j][kc], acco[j], 0, 0, 0);

      asm volatile("s_waitcnt lgkmcnt(0)" ::: "memory");
    };

    bf16x8 kA[4][2], vA[4][2], kB[4][2], vB[4][2];
    prefetch(kA, vA, 0);
    int it = 0;
    for (; it + 1 < niter; it += 2) {
      prefetch(kB, vB, (it + 1) * 64);
      compute(kA, vA, it * 64);
      if (it + 2 < niter) prefetch(kA, vA, (it + 2) * 64);
      compute(kB, vB, (it + 1) * 64);
    }
    if (it < niter) compute(kA, vA, it * 64);

    // epilogue
#pragma unroll
    for (int j = 0; j < 4; ++j)
#pragma unroll
      for (int r = 0; r < 4; ++r) {
        const int q = qbase + g * 4 + r;
        const int dd = j * 16 + l15;
        const float v = acco[j][r] / lrow[r];
        AO[((size_t)(b * SEQN + q)) * DMOD + h * DHEAD + dd] = (bf16)v;
      }
  };

  run_phase(p);
  run_phase(31 - p);
}

// ---------------------------------------------------------------- out gemm
__global__ __launch_bounds__(256) void gemm_out(
    const bf16* __restrict__ AO, const bf16* __restrict__ Wob,
    const float* __restrict__ bo, float* __restrict__ out)
{
  __shared__ bf16 sA[128 * 32];
  __shared__ bf16 sB[128 * 32];

  const int t = threadIdx.x;
  const int lane = t & 63, l15 = lane & 15, g = lane >> 4;
  const int wave = t >> 6, wm = wave >> 1, wn = wave & 1;
  const int tileM = blockIdx.y * 128, tileN = blockIdx.x * 128;

  f32x4 acc[4][4] = {};

  const int srow = t >> 2, schk = t & 3;
  const bf16* gA = AO + (size_t)(tileM + srow) * DMOD + schk * 8;
  const bf16* gB = Wob + (size_t)(tileN + srow) * DMOD + schk * 8;
  bf16* lA = sA + t * 8;
  bf16* lB = sB + t * 8;

  for (int k0 = 0; k0 < DMOD; k0 += 32) {
    __syncthreads();
    gload_lds16(gA + k0, lA);
    gload_lds16(gA + k0 + 64 * DMOD, lA + 2048);
    gload_lds16(gB + k0, lB);
    gload_lds16(gB + k0 + 64 * DMOD, lB + 2048);
    __syncthreads();
    bf16x8 af[4], bfr[4];
#pragma unroll
    for (int i = 0; i < 4; ++i)
      af[i] = *(const bf16x8*)(sA + (wm * 64 + i * 16 + l15) * 32 + g * 8);
#pragma unroll
    for (int j = 0; j < 4; ++j)
      bfr[j] = *(const bf16x8*)(sB + (wn * 64 + j * 16 + l15) * 32 + g * 8);
#pragma unroll
    for (int i = 0; i < 4; ++i)
#pragma unroll
      for (int j = 0; j < 4; ++j)
        acc[i][j] = __builtin_amdgcn_mfma_f32_16x16x32_bf16(af[i], bfr[j], acc[i][j], 0, 0, 0);
  }

#pragma unroll
  for (int j = 0; j < 4; ++j) {
    const int col = tileN + wn * 64 + j * 16 + l15;
    const float bcol = bo[col];
#pragma unroll
    for (int i = 0; i < 4; ++i)
#pragma unroll
      for (int r = 0; r < 4; ++r) {
        const int row = tileM + wm * 64 + i * 16 + g * 4 + r;
        out[(size_t)row * DMOD + col] = acc[i][j][r] + bcol;
      }
  }
}

// ---------------------------------------------------------------- launch
extern "C" void kernel_launch(void* const* d_in, const int* in_sizes, int n_in,
                              void* d_out, int out_size, void* d_ws, size_t ws_size,
                              hipStream_t stream)
{
  (void)in_sizes; (void)n_in; (void)out_size; (void)ws_size;
  const float* X  = (const float*)d_in[0];
  const float* Wq = (const float*)d_in[1];
  const float* bq = (const float*)d_in[2];
  const float* Wk = (const float*)d_in[3];
  const float* bk = (const float*)d_in[4];
  const float* Wv = (const float*)d_in[5];
  const float* bv = (const float*)d_in[6];
  const float* Wo = (const float*)d_in[7];
  const float* bo = (const float*)d_in[8];

  char* ws = (char*)d_ws;
  float* ctab = (float*)(ws + 0);
  float* stab = (float*)(ws + 262144);
  bf16* Xb  = (bf16*)(ws + 524288);
  bf16* Wqb = (bf16*)(ws + 8912896);
  bf16* Wkb = (bf16*)(ws + 11010048);
  bf16* Wvb = (bf16*)(ws + 13107200);
  bf16* Wob = (bf16*)(ws + 15204352);
  bf16* Qb  = (bf16*)(ws + 17301504);
  bf16* Kb  = (bf16*)(ws + 25690112);
  bf16* Vtb = (bf16*)(ws + 34078720);   // 32*64*2080*2 = 8519680 bytes
  bf16* AO  = (bf16*)(ws + 42598400);

  prep_kernel<<<1024, 256, 0, stream>>>(X, Wq, Wk, Wv, Wo, Xb, Wqb, Wkb, Wvb, Wob, ctab, stab);
  gemm_qkv<<<dim3(8, 32, 3), 256, 0, stream>>>(Xb, Wqb, Wkb, Wvb, bq, bk, bv, ctab, stab, Qb, Kb, Vtb);
  attn_kernel<<<512, 256, 0, stream>>>(Qb, Kb, Vtb, AO);
  gemm_out<<<dim3(8, 32), 256, 0, stream>>>(AO, Wob, bo, (float*)d_out);
}

// Round 8
// 162.857 us; speedup vs baseline: 1.3595x; 1.2664x over previous
//
#include <hip/hip_runtime.h>
#include <hip/hip_bf16.h>
#include <stdint.h>
#include <math.h>

// CausalMultiheadRoPEAttn: B=2, S=2048, D=1024, H=16, Dh=64
// prep (bf16 casts + rope table) -> fused QKV gemm (+bias+rope, V transposed,
// padded stride) -> flash attention v2: swapped-operand 32x32x16 MFMA,
// in-register softmax; ALL cross-half exchanges via __shfl_xor(.,32)
// (defined semantics; no raw permlane asm), explicit hi-half selects.
// Zero LDS / zero barriers in attention. -> out gemm.

typedef __bf16 bf16;
typedef __attribute__((ext_vector_type(4))) __bf16 bf16x4;
typedef __attribute__((ext_vector_type(8))) __bf16 bf16x8;
typedef __attribute__((ext_vector_type(4))) float f32x4;
typedef __attribute__((ext_vector_type(16))) float f32x16;
typedef __attribute__((ext_vector_type(4))) uint32_t u32x4;

#define SEQN 2048
#define DMOD 1024
#define NHEAD 16
#define DHEAD 64
#define MTOT 4096
#define VSTR 2080   // padded Vt row stride (elements)
// 0.125 * log2(e): scores land in log2 domain -> softmax uses exp2
#define QSCALE_LOG2E 0.18033688011112042f

__device__ __forceinline__ void gload_lds16(const bf16* g, bf16* l) {
  __builtin_amdgcn_global_load_lds(
      (const __attribute__((address_space(1))) uint32_t*)g,
      (__attribute__((address_space(3))) uint32_t*)l,
      16, 0, 0);
}

__device__ __forceinline__ uint32_t cvtpk(float lo, float hi) {
  uint32_t r;
  asm("v_cvt_pk_bf16_f32 %0, %1, %2" : "=v"(r) : "v"(lo), "v"(hi));
  return r;
}

// ---------------------------------------------------------------- prep
__global__ __launch_bounds__(256) void prep_kernel(
    const float* __restrict__ X,
    const float* __restrict__ Wq, const float* __restrict__ Wk,
    const float* __restrict__ Wv, const float* __restrict__ Wo,
    bf16* __restrict__ Xb, bf16* __restrict__ Wqb, bf16* __restrict__ Wkb,
    bf16* __restrict__ Wvb, bf16* __restrict__ Wob,
    float* __restrict__ ctab, float* __restrict__ stab)
{
  const int tid = blockIdx.x * blockDim.x + threadIdx.x;
  const int nth = gridDim.x * blockDim.x;

  const float4* X4 = (const float4*)X;
  for (int i = tid; i < MTOT * DMOD / 4; i += nth) {
    float4 v = X4[i];
    bf16x4 o = { (bf16)v.x, (bf16)v.y, (bf16)v.z, (bf16)v.w };
    *(bf16x4*)(Xb + (size_t)i * 4) = o;
  }
  const float4* q4 = (const float4*)Wq;
  const float4* k4 = (const float4*)Wk;
  const float4* v4 = (const float4*)Wv;
  const float4* o4 = (const float4*)Wo;
  for (int i = tid; i < DMOD * DMOD / 4; i += nth) {
    float4 a = q4[i];
    float4 b = k4[i];
    float4 c = v4[i];
    float4 d = o4[i];
    *(bf16x4*)(Wqb + (size_t)i * 4) = bf16x4{ (bf16)a.x, (bf16)a.y, (bf16)a.z, (bf16)a.w };
    *(bf16x4*)(Wkb + (size_t)i * 4) = bf16x4{ (bf16)b.x, (bf16)b.y, (bf16)b.z, (bf16)b.w };
    *(bf16x4*)(Wvb + (size_t)i * 4) = bf16x4{ (bf16)c.x, (bf16)c.y, (bf16)c.z, (bf16)c.w };
    *(bf16x4*)(Wob + (size_t)i * 4) = bf16x4{ (bf16)d.x, (bf16)d.y, (bf16)d.z, (bf16)d.w };
  }
  for (int i = tid; i < SEQN * 32; i += nth) {
    const int s = i >> 5, p = i & 31;
    const float invf = (float)pow(10000.0, -(double)p / 32.0);
    const float ang = (float)s * invf;
    float sv, cv;
    sincosf(ang, &sv, &cv);
    ctab[i] = cv;
    stab[i] = sv;
  }
}

// ---------------------------------------------------------------- QKV gemm
__global__ __launch_bounds__(256) void gemm_qkv(
    const bf16* __restrict__ Xb,
    const bf16* __restrict__ Wqb, const bf16* __restrict__ Wkb, const bf16* __restrict__ Wvb,
    const float* __restrict__ bq, const float* __restrict__ bk, const float* __restrict__ bv,
    const float* __restrict__ ctab, const float* __restrict__ stab,
    bf16* __restrict__ Qb, bf16* __restrict__ Kb, bf16* __restrict__ Vtb)
{
  __shared__ bf16 sA[128 * 32];
  __shared__ bf16 sB[128 * 32];

  const int z = blockIdx.z;
  const bf16* Bm = (z == 0) ? Wqb : (z == 1) ? Wkb : Wvb;
  const float* bias = (z == 0) ? bq : (z == 1) ? bk : bv;

  const int t = threadIdx.x;
  const int lane = t & 63, l15 = lane & 15, g = lane >> 4;
  const int wave = t >> 6, wm = wave >> 1, wn = wave & 1;
  const int tileM = blockIdx.y * 128, tileN = blockIdx.x * 128;

  f32x4 acc[4][4] = {};

  const int srow = t >> 2, schk = t & 3;
  const bf16* gA = Xb + (size_t)(tileM + srow) * DMOD + schk * 8;
  const bf16* gB = Bm + (size_t)(tileN + srow) * DMOD + schk * 8;
  bf16* lA = sA + t * 8;
  bf16* lB = sB + t * 8;

  for (int k0 = 0; k0 < DMOD; k0 += 32) {
    __syncthreads();
    gload_lds16(gA + k0, lA);
    gload_lds16(gA + k0 + 64 * DMOD, lA + 2048);
    gload_lds16(gB + k0, lB);
    gload_lds16(gB + k0 + 64 * DMOD, lB + 2048);
    __syncthreads();
    bf16x8 af[4], bfr[4];
#pragma unroll
    for (int i = 0; i < 4; ++i)
      af[i] = *(const bf16x8*)(sA + (wm * 64 + i * 16 + l15) * 32 + g * 8);
#pragma unroll
    for (int j = 0; j < 4; ++j)
      bfr[j] = *(const bf16x8*)(sB + (wn * 64 + j * 16 + l15) * 32 + g * 8);
#pragma unroll
    for (int i = 0; i < 4; ++i)
#pragma unroll
      for (int j = 0; j < 4; ++j)
        acc[i][j] = __builtin_amdgcn_mfma_f32_16x16x32_bf16(af[i], bfr[j], acc[i][j], 0, 0, 0);
  }

#pragma unroll
  for (int j = 0; j < 4; ++j) {
    const int col = tileN + wn * 64 + j * 16 + l15;
    const float bcol = bias[col];
    const int h = col >> 6, d = col & 63;
#pragma unroll
    for (int i = 0; i < 4; ++i) {
#pragma unroll
      for (int r = 0; r < 4; ++r) {
        const int row = tileM + wm * 64 + i * 16 + g * 4 + r;
        const int b = row >> 11, s = row & (SEQN - 1);
        const float v = acc[i][j][r] + bcol;
        if (z != 2) {
          const int pair = d >> 1;
          const float cv = ctab[s * 32 + pair];
          const float sv = stab[s * 32 + pair];
          const float partner = __shfl_xor(v, 1);
          float rv = (d & 1) ? (partner * sv + v * cv) : (v * cv - partner * sv);
          if (z == 0) rv *= QSCALE_LOG2E;   // fold softmax scale+log2e into Q
          bf16* dst = (z == 0) ? Qb : Kb;
          dst[(((size_t)(b * NHEAD + h)) * SEQN + s) * DHEAD + d] = (bf16)rv;
        } else {
          Vtb[(((size_t)(b * NHEAD + h)) * DHEAD + d) * VSTR + s] = (bf16)v;
        }
      }
    }
  }
}

// ---------------------------------------------------------------- attention
// 256 blocks (8 qtile-pairs x 32 bh; bid%8==bh%8 -> XCD-local heads), 4 waves.
// Wave owns 32 q-rows; pair (p,15-p) with wave<->row-slot swap: exactly 33
// KV-64 iterations per wave. Swapped-operand 32x32x16 MFMA: scores land
// col=q=lane&31; softmax in-register (in-lane tree + one shfl_xor(32));
// P B-frags via cvt_pk + shfl_xor(32) + explicit hi-half select; PV uses Vt
// as A-operand so acc is also col=q. No LDS, no barriers.
__global__ __launch_bounds__(256, 1) void attn_kernel(
    const bf16* __restrict__ Qb, const bf16* __restrict__ Kb,
    const bf16* __restrict__ Vt, bf16* __restrict__ AO)
{
  const int t = threadIdx.x;
  const int lane = t & 63, l31 = lane & 31, hi = lane >> 5;
  const int wave = t >> 6;

  const int bid = blockIdx.x;
  const int p = bid >> 5, bh = bid & 31;   // bid%8 == bh%8

  const bf16* Kp = Kb + (size_t)bh * SEQN * DHEAD;
  const bf16* Vp = Vt + (size_t)bh * DHEAD * VSTR;
  const bf16* Qp = Qb + (size_t)bh * SEQN * DHEAD;
  const int b = bh >> 4, h = bh & 15;

  // K A-frag: row=key=l31, k=8hi+e (d=16ch+8hi+e); Vt A-frag: row=d=l31,
  // k=8hi+e (key=kv0+16c+8hi+e)
  auto prefetch = [&](bf16x8 (&K)[2][4], bf16x8 (&V)[2][4], int kv0) {
#pragma unroll
    for (int s = 0; s < 2; ++s)
#pragma unroll
      for (int ch = 0; ch < 4; ++ch)
        K[s][ch] = *(const bf16x8*)(Kp + (size_t)(kv0 + 32 * s + l31) * DHEAD + 16 * ch + 8 * hi);
#pragma unroll
    for (int dblk = 0; dblk < 2; ++dblk)
#pragma unroll
      for (int c = 0; c < 4; ++c)
        V[dblk][c] = *(const bf16x8*)(Vp + (size_t)(dblk * 32 + l31) * VSTR + kv0 + 16 * c + 8 * hi);
  };

  auto run_phase = [&](int qtile, int wrow) {
    const int qbase = qtile * 128 + wrow * 32;
    const int qg = qbase + l31;            // this lane's q-row
    const int niter = (qbase >> 6) + 1;    // KV-64 tiles covering qbase+31

    bf16x8 qf[4];   // Q B-frag: col=q=l31, k=8hi+e (d=16ch+8hi+e)
#pragma unroll
    for (int ch = 0; ch < 4; ++ch)
      qf[ch] = *(const bf16x8*)(Qp + (size_t)qg * DHEAD + 16 * ch + 8 * hi);

    f32x16 a0 = {}, a1 = {};
    float m = -1e30f, l = 0.f;

    auto compute = [&](const bf16x8 (&K)[2][4], const bf16x8 (&V)[2][4], int kv0) {
      f32x16 s0 = {}, s1 = {};
#pragma unroll
      for (int ch = 0; ch < 4; ++ch) {
        s0 = __builtin_amdgcn_mfma_f32_32x32x16_bf16(K[0][ch], qf[ch], s0, 0, 0, 0);
        s1 = __builtin_amdgcn_mfma_f32_32x32x16_bf16(K[1][ch], qf[ch], s1, 0, 0, 0);
      }
      // tv[i]: score for key offset 32*(i>>4) + (i&3) + 8*((i>>2)&3) + 4*hi
      float tv[32];
#pragma unroll
      for (int i = 0; i < 16; ++i) { tv[i] = s0[i]; tv[16 + i] = s1[i]; }

      if (kv0 + 63 > qbase) {   // diagonal tile(s): causal mask (key > q)
#pragma unroll
        for (int i = 0; i < 32; ++i) {
          const int key = kv0 + 32 * (i >> 4) + ((i & 3) + 8 * ((i >> 2) & 3) + 4 * hi);
          if (key > qg) tv[i] = -1e30f;
        }
      }

      // row max: in-lane tree, then combine with partner half via shfl_xor(32)
      float red[16];
#pragma unroll
      for (int i = 0; i < 16; ++i) red[i] = fmaxf(tv[i], tv[i + 16]);
#pragma unroll
      for (int st = 8; st >= 1; st >>= 1)
#pragma unroll
        for (int i = 0; i < st; ++i) red[i] = fmaxf(red[i], red[i + st]);
      const float tmax = fmaxf(red[0], __shfl_xor(red[0], 32));
      const float mnew = fmaxf(m, tmax);
      const float alpha = __builtin_amdgcn_exp2f(m - mnew);
      m = mnew;

      // p = exp2(s - m), row sum (tree + shfl_xor(32))
#pragma unroll
      for (int i = 0; i < 32; ++i) tv[i] = __builtin_amdgcn_exp2f(tv[i] - mnew);
#pragma unroll
      for (int i = 0; i < 16; ++i) red[i] = tv[i] + tv[i + 16];
#pragma unroll
      for (int st = 8; st >= 1; st >>= 1)
#pragma unroll
        for (int i = 0; i < st; ++i) red[i] += red[i + st];
      l = l * alpha + (red[0] + __shfl_xor(red[0], 32));

#pragma unroll
      for (int i = 0; i < 16; ++i) { a0[i] *= alpha; a1[i] *= alpha; }

      // P B-frag, chunk c: lane (q,hi) needs keys 16c+8hi+e, e=0..7.
      //   e=0..3 come from lane (q,0) at tv[base(2c+hi)+e]
      //   e=4..7 come from lane (q,1) at tv[base(2c+hi)+(e-4)]
      // where base(m)=4*(m&3)+16*(m>>2); key(tv idx base(m)+e', hi_own) =
      // e' + 8*m + 4*hi_own (verified identity). Pack own words, exchange
      // across the half boundary with shfl_xor(32), select by hi.
#pragma unroll
      for (int c = 0; c < 4; ++c) {
        const int b0 = (c & 1) * 8 + (c >> 1) * 16;   // base(2c); base(2c+1)=b0+4
        const uint32_t P0  = cvtpk(tv[b0 + 0], tv[b0 + 1]);
        const uint32_t P0b = cvtpk(tv[b0 + 2], tv[b0 + 3]);
        const uint32_t P1  = cvtpk(tv[b0 + 4], tv[b0 + 5]);
        const uint32_t P1b = cvtpk(tv[b0 + 6], tv[b0 + 7]);
        const uint32_t sP0  = (uint32_t)__shfl_xor((int)P0, 32);
        const uint32_t sP0b = (uint32_t)__shfl_xor((int)P0b, 32);
        const uint32_t sP1  = (uint32_t)__shfl_xor((int)P1, 32);
        const uint32_t sP1b = (uint32_t)__shfl_xor((int)P1b, 32);
        u32x4 pw;
        pw[0] = hi ? sP1  : P0;    // e0,e1: from lane (q,0) @ base(2c+hi)
        pw[1] = hi ? sP1b : P0b;   // e2,e3
        pw[2] = hi ? P1   : sP0;   // e4,e5: from lane (q,1) @ base(2c+hi)
        pw[3] = hi ? P1b  : sP0b;  // e6,e7
        const bf16x8 pf = __builtin_bit_cast(bf16x8, pw);
        a0 = __builtin_amdgcn_mfma_f32_32x32x16_bf16(V[0][c], pf, a0, 0, 0, 0);
        a1 = __builtin_amdgcn_mfma_f32_32x32x16_bf16(V[1][c], pf, a1, 0, 0, 0);
      }
    };

    bf16x8 kA[2][4], vA[2][4], kB[2][4], vB[2][4];
    prefetch(kA, vA, 0);
    int it = 0;
    for (; it + 1 < niter; it += 2) {
      prefetch(kB, vB, (it + 1) * 64);
      compute(kA, vA, it * 64);
      if (it + 2 < niter) prefetch(kA, vA, (it + 2) * 64);
      compute(kB, vB, (it + 1) * 64);
    }
    if (it < niter) compute(kA, vA, it * 64);

    // epilogue: acc col=q=l31, row=d=(reg&3)+8*(reg>>2)+4hi (+32*dblk)
    const float linv = 1.f / l;
    const size_t rowoff = ((size_t)(b * SEQN + qg)) * DMOD + h * DHEAD;
#pragma unroll
    for (int dblk = 0; dblk < 2; ++dblk) {
      const f32x16& av = dblk ? a1 : a0;
#pragma unroll
      for (int rg = 0; rg < 4; ++rg) {
        const int d0 = dblk * 32 + rg * 8 + 4 * hi;
        bf16x4 ov = { (bf16)(av[rg * 4 + 0] * linv), (bf16)(av[rg * 4 + 1] * linv),
                      (bf16)(av[rg * 4 + 2] * linv), (bf16)(av[rg * 4 + 3] * linv) };
        *(bf16x4*)(AO + rowoff + d0) = ov;
      }
    }
  };

  run_phase(p, wave);
  run_phase(15 - p, 3 - wave);
}

// ---------------------------------------------------------------- out gemm
__global__ __launch_bounds__(256) void gemm_out(
    const bf16* __restrict__ AO, const bf16* __restrict__ Wob,
    const float* __restrict__ bo, float* __restrict__ out)
{
  __shared__ bf16 sA[128 * 32];
  __shared__ bf16 sB[128 * 32];

  const int t = threadIdx.x;
  const int lane = t & 63, l15 = lane & 15, g = lane >> 4;
  const int wave = t >> 6, wm = wave >> 1, wn = wave & 1;
  const int tileM = blockIdx.y * 128, tileN = blockIdx.x * 128;

  f32x4 acc[4][4] = {};

  const int srow = t >> 2, schk = t & 3;
  const bf16* gA = AO + (size_t)(tileM + srow) * DMOD + schk * 8;
  const bf16* gB = Wob + (size_t)(tileN + srow) * DMOD + schk * 8;
  bf16* lA = sA + t * 8;
  bf16* lB = sB + t * 8;

  for (int k0 = 0; k0 < DMOD; k0 += 32) {
    __syncthreads();
    gload_lds16(gA + k0, lA);
    gload_lds16(gA + k0 + 64 * DMOD, lA + 2048);
    gload_lds16(gB + k0, lB);
    gload_lds16(gB + k0 + 64 * DMOD, lB + 2048);
    __syncthreads();
    bf16x8 af[4], bfr[4];
#pragma unroll
    for (int i = 0; i < 4; ++i)
      af[i] = *(const bf16x8*)(sA + (wm * 64 + i * 16 + l15) * 32 + g * 8);
#pragma unroll
    for (int j = 0; j < 4; ++j)
      bfr[j] = *(const bf16x8*)(sB + (wn * 64 + j * 16 + l15) * 32 + g * 8);
#pragma unroll
    for (int i = 0; i < 4; ++i)
#pragma unroll
      for (int j = 0; j < 4; ++j)
        acc[i][j] = __builtin_amdgcn_mfma_f32_16x16x32_bf16(af[i], bfr[j], acc[i][j], 0, 0, 0);
  }

#pragma unroll
  for (int j = 0; j < 4; ++j) {
    const int col = tileN + wn * 64 + j * 16 + l15;
    const float bcol = bo[col];
#pragma unroll
    for (int i = 0; i < 4; ++i)
#pragma unroll
      for (int r = 0; r < 4; ++r) {
        const int row = tileM + wm * 64 + i * 16 + g * 4 + r;
        out[(size_t)row * DMOD + col] = acc[i][j][r] + bcol;
      }
  }
}

// ---------------------------------------------------------------- launch
extern "C" void kernel_launch(void* const* d_in, const int* in_sizes, int n_in,
                              void* d_out, int out_size, void* d_ws, size_t ws_size,
                              hipStream_t stream)
{
  (void)in_sizes; (void)n_in; (void)out_size; (void)ws_size;
  const float* X  = (const float*)d_in[0];
  const float* Wq = (const float*)d_in[1];
  const float* bq = (const float*)d_in[2];
  const float* Wk = (const float*)d_in[3];
  const float* bk = (const float*)d_in[4];
  const float* Wv = (const float*)d_in[5];
  const float* bv = (const float*)d_in[6];
  const float* Wo = (const float*)d_in[7];
  const float* bo = (const float*)d_in[8];

  char* ws = (char*)d_ws;
  float* ctab = (float*)(ws + 0);
  float* stab = (float*)(ws + 262144);
  bf16* Xb  = (bf16*)(ws + 524288);
  bf16* Wqb = (bf16*)(ws + 8912896);
  bf16* Wkb = (bf16*)(ws + 11010048);
  bf16* Wvb = (bf16*)(ws + 13107200);
  bf16* Wob = (bf16*)(ws + 15204352);
  bf16* Qb  = (bf16*)(ws + 17301504);
  bf16* Kb  = (bf16*)(ws + 25690112);
  bf16* Vtb = (bf16*)(ws + 34078720);   // 32*64*2080*2 = 8519680 bytes
  bf16* AO  = (bf16*)(ws + 42598400);

  prep_kernel<<<1024, 256, 0, stream>>>(X, Wq, Wk, Wv, Wo, Xb, Wqb, Wkb, Wvb, Wob, ctab, stab);
  gemm_qkv<<<dim3(8, 32, 3), 256, 0, stream>>>(Xb, Wqb, Wkb, Wvb, bq, bk, bv, ctab, stab, Qb, Kb, Vtb);
  attn_kernel<<<256, 256, 0, stream>>>(Qb, Kb, Vtb, AO);
  gemm_out<<<dim3(8, 32), 256, 0, stream>>>(AO, Wob, bo, (float*)d_out);
}

// Round 9
// 141.975 us; speedup vs baseline: 1.5595x; 1.1471x over previous
//
#include <hip/hip_runtime.h>
#include <hip/hip_bf16.h>
#include <stdint.h>
#include <math.h>

// CausalMultiheadRoPEAttn: B=2, S=2048, D=1024, H=16, Dh=64
// prep (bf16 casts + rope table) -> fused QKV gemm (+bias+rope, V transposed,
// padded stride; counted-vmcnt depth-2 pipelined K-loop, raw barriers)
// -> flash attention (swapped-operand 32x32x16 MFMA, in-register softmax,
// zero LDS/barriers) -> out gemm (same pipelined K-loop).

typedef __bf16 bf16;
typedef __attribute__((ext_vector_type(4))) __bf16 bf16x4;
typedef __attribute__((ext_vector_type(8))) __bf16 bf16x8;
typedef __attribute__((ext_vector_type(4))) float f32x4;
typedef __attribute__((ext_vector_type(16))) float f32x16;
typedef __attribute__((ext_vector_type(4))) uint32_t u32x4;

#define SEQN 2048
#define DMOD 1024
#define NHEAD 16
#define DHEAD 64
#define MTOT 4096
#define VSTR 2080   // padded Vt row stride (elements)
// 0.125 * log2(e): scores land in log2 domain -> softmax uses exp2
#define QSCALE_LOG2E 0.18033688011112042f

__device__ __forceinline__ void gload_lds16(const bf16* g, bf16* l) {
  __builtin_amdgcn_global_load_lds(
      (const __attribute__((address_space(1))) uint32_t*)g,
      (__attribute__((address_space(3))) uint32_t*)l,
      16, 0, 0);
}

__device__ __forceinline__ uint32_t cvtpk(float lo, float hi) {
  uint32_t r;
  asm("v_cvt_pk_bf16_f32 %0, %1, %2" : "=v"(r) : "v"(lo), "v"(hi));
  return r;
}

// ---------------------------------------------------------------- prep
__global__ __launch_bounds__(256) void prep_kernel(
    const float* __restrict__ X,
    const float* __restrict__ Wq, const float* __restrict__ Wk,
    const float* __restrict__ Wv, const float* __restrict__ Wo,
    bf16* __restrict__ Xb, bf16* __restrict__ Wqb, bf16* __restrict__ Wkb,
    bf16* __restrict__ Wvb, bf16* __restrict__ Wob,
    float* __restrict__ ctab, float* __restrict__ stab)
{
  const int tid = blockIdx.x * blockDim.x + threadIdx.x;
  const int nth = gridDim.x * blockDim.x;

  const float4* X4 = (const float4*)X;
  for (int i = tid; i < MTOT * DMOD / 4; i += nth) {
    float4 v = X4[i];
    bf16x4 o = { (bf16)v.x, (bf16)v.y, (bf16)v.z, (bf16)v.w };
    *(bf16x4*)(Xb + (size_t)i * 4) = o;
  }
  const float4* q4 = (const float4*)Wq;
  const float4* k4 = (const float4*)Wk;
  const float4* v4 = (const float4*)Wv;
  const float4* o4 = (const float4*)Wo;
  for (int i = tid; i < DMOD * DMOD / 4; i += nth) {
    float4 a = q4[i];
    float4 b = k4[i];
    float4 c = v4[i];
    float4 d = o4[i];
    *(bf16x4*)(Wqb + (size_t)i * 4) = bf16x4{ (bf16)a.x, (bf16)a.y, (bf16)a.z, (bf16)a.w };
    *(bf16x4*)(Wkb + (size_t)i * 4) = bf16x4{ (bf16)b.x, (bf16)b.y, (bf16)b.z, (bf16)b.w };
    *(bf16x4*)(Wvb + (size_t)i * 4) = bf16x4{ (bf16)c.x, (bf16)c.y, (bf16)c.z, (bf16)c.w };
    *(bf16x4*)(Wob + (size_t)i * 4) = bf16x4{ (bf16)d.x, (bf16)d.y, (bf16)d.z, (bf16)d.w };
  }
  for (int i = tid; i < SEQN * 32; i += nth) {
    const int s = i >> 5, p = i & 31;
    const float invf = (float)pow(10000.0, -(double)p / 32.0);
    const float ang = (float)s * invf;
    float sv, cv;
    sincosf(ang, &sv, &cv);
    ctab[i] = cv;
    stab[i] = sv;
  }
}

// ---------------------------------------------------------------- QKV gemm
// 128x128 tile, BK=32, 3-buffer LDS pipeline with counted vmcnt: tile s+2's
// global_load_lds stay in flight across the barriers (never drain to 0 in
// steady state); raw s_barrier (no compiler vmcnt(0) drain).
__global__ __launch_bounds__(256) void gemm_qkv(
    const bf16* __restrict__ Xb,
    const bf16* __restrict__ Wqb, const bf16* __restrict__ Wkb, const bf16* __restrict__ Wvb,
    const float* __restrict__ bq, const float* __restrict__ bk, const float* __restrict__ bv,
    const float* __restrict__ ctab, const float* __restrict__ stab,
    bf16* __restrict__ Qb, bf16* __restrict__ Kb, bf16* __restrict__ Vtb)
{
  __shared__ bf16 sA[3][128 * 32];
  __shared__ bf16 sB[3][128 * 32];

  const int z = blockIdx.z;
  const bf16* Bm = (z == 0) ? Wqb : (z == 1) ? Wkb : Wvb;
  const float* bias = (z == 0) ? bq : (z == 1) ? bk : bv;

  const int t = threadIdx.x;
  const int lane = t & 63, l15 = lane & 15, g = lane >> 4;
  const int wave = t >> 6, wm = wave >> 1, wn = wave & 1;
  const int tileM = blockIdx.y * 128, tileN = blockIdx.x * 128;

  f32x4 acc[4][4] = {};

  const bf16* gA = Xb + (size_t)(tileM + (t >> 2)) * DMOD + (t & 3) * 8;
  const bf16* gB = Bm + (size_t)(tileN + (t >> 2)) * DMOD + (t & 3) * 8;

  auto stage = [&](int buf, int k0) {
    gload_lds16(gA + k0, &sA[buf][t * 8]);
    gload_lds16(gA + k0 + 64 * DMOD, &sA[buf][2048 + t * 8]);
    gload_lds16(gB + k0, &sB[buf][t * 8]);
    gload_lds16(gB + k0 + 64 * DMOD, &sB[buf][2048 + t * 8]);
  };

  stage(0, 0);
  stage(1, 32);

  const int NS = DMOD / 32;   // 32 K-steps
  int cur = 0;
  for (int s = 0; s < NS; ++s) {
    if (s + 2 < NS) {
      int pf = cur + 2; if (pf >= 3) pf -= 3;
      stage(pf, (s + 2) * 32);
      asm volatile("s_waitcnt vmcnt(8)" ::: "memory");   // tile s landed; s+1,s+2 in flight
    } else if (s + 1 < NS) {
      asm volatile("s_waitcnt vmcnt(4)" ::: "memory");
    } else {
      asm volatile("s_waitcnt vmcnt(0)" ::: "memory");
    }
    __builtin_amdgcn_s_barrier();
    asm volatile("" ::: "memory");

    const bf16* cA = sA[cur];
    const bf16* cB = sB[cur];
    bf16x8 af[4], bfr[4];
#pragma unroll
    for (int i = 0; i < 4; ++i)
      af[i] = *(const bf16x8*)(cA + (wm * 64 + i * 16 + l15) * 32 + g * 8);
#pragma unroll
    for (int j = 0; j < 4; ++j)
      bfr[j] = *(const bf16x8*)(cB + (wn * 64 + j * 16 + l15) * 32 + g * 8);
#pragma unroll
    for (int i = 0; i < 4; ++i)
#pragma unroll
      for (int j = 0; j < 4; ++j)
        acc[i][j] = __builtin_amdgcn_mfma_f32_16x16x32_bf16(af[i], bfr[j], acc[i][j], 0, 0, 0);

    asm volatile("" ::: "memory");
    __builtin_amdgcn_s_barrier();   // buf `cur` free for reuse at s+1's stage
    cur = (cur == 2) ? 0 : cur + 1;
  }

#pragma unroll
  for (int j = 0; j < 4; ++j) {
    const int col = tileN + wn * 64 + j * 16 + l15;
    const float bcol = bias[col];
    const int h = col >> 6, d = col & 63;
#pragma unroll
    for (int i = 0; i < 4; ++i) {
#pragma unroll
      for (int r = 0; r < 4; ++r) {
        const int row = tileM + wm * 64 + i * 16 + g * 4 + r;
        const int b = row >> 11, s = row & (SEQN - 1);
        const float v = acc[i][j][r] + bcol;
        if (z != 2) {
          const int pair = d >> 1;
          const float cv = ctab[s * 32 + pair];
          const float sv = stab[s * 32 + pair];
          const float partner = __shfl_xor(v, 1);
          float rv = (d & 1) ? (partner * sv + v * cv) : (v * cv - partner * sv);
          if (z == 0) rv *= QSCALE_LOG2E;   // fold softmax scale+log2e into Q
          bf16* dst = (z == 0) ? Qb : Kb;
          dst[(((size_t)(b * NHEAD + h)) * SEQN + s) * DHEAD + d] = (bf16)rv;
        } else {
          Vtb[(((size_t)(b * NHEAD + h)) * DHEAD + d) * VSTR + s] = (bf16)v;
        }
      }
    }
  }
}

// ---------------------------------------------------------------- attention
// 256 blocks (8 qtile-pairs x 32 bh; bid%8==bh%8 -> XCD-local heads), 4 waves.
// Wave owns 32 q-rows; pair (p,15-p) with wave<->row-slot swap: exactly 33
// KV-64 iterations per wave. Swapped-operand 32x32x16 MFMA: scores land
// col=q=lane&31; softmax in-register (in-lane tree + one shfl_xor(32));
// P B-frags via cvt_pk + shfl_xor(32) + explicit hi-half select; PV uses Vt
// as A-operand so acc is also col=q. No LDS, no barriers.
__global__ __launch_bounds__(256, 1) void attn_kernel(
    const bf16* __restrict__ Qb, const bf16* __restrict__ Kb,
    const bf16* __restrict__ Vt, bf16* __restrict__ AO)
{
  const int t = threadIdx.x;
  const int lane = t & 63, l31 = lane & 31, hi = lane >> 5;
  const int wave = t >> 6;

  const int bid = blockIdx.x;
  const int p = bid >> 5, bh = bid & 31;   // bid%8 == bh%8

  const bf16* Kp = Kb + (size_t)bh * SEQN * DHEAD;
  const bf16* Vp = Vt + (size_t)bh * DHEAD * VSTR;
  const bf16* Qp = Qb + (size_t)bh * SEQN * DHEAD;
  const int b = bh >> 4, h = bh & 15;

  auto prefetch = [&](bf16x8 (&K)[2][4], bf16x8 (&V)[2][4], int kv0) {
#pragma unroll
    for (int s = 0; s < 2; ++s)
#pragma unroll
      for (int ch = 0; ch < 4; ++ch)
        K[s][ch] = *(const bf16x8*)(Kp + (size_t)(kv0 + 32 * s + l31) * DHEAD + 16 * ch + 8 * hi);
#pragma unroll
    for (int dblk = 0; dblk < 2; ++dblk)
#pragma unroll
      for (int c = 0; c < 4; ++c)
        V[dblk][c] = *(const bf16x8*)(Vp + (size_t)(dblk * 32 + l31) * VSTR + kv0 + 16 * c + 8 * hi);
  };

  auto run_phase = [&](int qtile, int wrow) {
    const int qbase = qtile * 128 + wrow * 32;
    const int qg = qbase + l31;            // this lane's q-row
    const int niter = (qbase >> 6) + 1;    // KV-64 tiles covering qbase+31

    bf16x8 qf[4];   // Q B-frag: col=q=l31, k=8hi+e (d=16ch+8hi+e)
#pragma unroll
    for (int ch = 0; ch < 4; ++ch)
      qf[ch] = *(const bf16x8*)(Qp + (size_t)qg * DHEAD + 16 * ch + 8 * hi);

    f32x16 a0 = {}, a1 = {};
    float m = -1e30f, l = 0.f;

    auto compute = [&](const bf16x8 (&K)[2][4], const bf16x8 (&V)[2][4], int kv0) {
      f32x16 s0 = {}, s1 = {};
#pragma unroll
      for (int ch = 0; ch < 4; ++ch) {
        s0 = __builtin_amdgcn_mfma_f32_32x32x16_bf16(K[0][ch], qf[ch], s0, 0, 0, 0);
        s1 = __builtin_amdgcn_mfma_f32_32x32x16_bf16(K[1][ch], qf[ch], s1, 0, 0, 0);
      }
      // tv[i]: score for key offset 32*(i>>4) + (i&3) + 8*((i>>2)&3) + 4*hi
      float tv[32];
#pragma unroll
      for (int i = 0; i < 16; ++i) { tv[i] = s0[i]; tv[16 + i] = s1[i]; }

      if (kv0 + 63 > qbase) {   // diagonal tile(s): causal mask (key > q)
#pragma unroll
        for (int i = 0; i < 32; ++i) {
          const int key = kv0 + 32 * (i >> 4) + ((i & 3) + 8 * ((i >> 2) & 3) + 4 * hi);
          if (key > qg) tv[i] = -1e30f;
        }
      }

      // row max: in-lane tree, then combine with partner half via shfl_xor(32)
      float red[16];
#pragma unroll
      for (int i = 0; i < 16; ++i) red[i] = fmaxf(tv[i], tv[i + 16]);
#pragma unroll
      for (int st = 8; st >= 1; st >>= 1)
#pragma unroll
        for (int i = 0; i < st; ++i) red[i] = fmaxf(red[i], red[i + st]);
      const float tmax = fmaxf(red[0], __shfl_xor(red[0], 32));
      const float mnew = fmaxf(m, tmax);
      const float alpha = __builtin_amdgcn_exp2f(m - mnew);
      m = mnew;

      // p = exp2(s - m), row sum (tree + shfl_xor(32))
#pragma unroll
      for (int i = 0; i < 32; ++i) tv[i] = __builtin_amdgcn_exp2f(tv[i] - mnew);
#pragma unroll
      for (int i = 0; i < 16; ++i) red[i] = tv[i] + tv[i + 16];
#pragma unroll
      for (int st = 8; st >= 1; st >>= 1)
#pragma unroll
        for (int i = 0; i < st; ++i) red[i] += red[i + st];
      l = l * alpha + (red[0] + __shfl_xor(red[0], 32));

#pragma unroll
      for (int i = 0; i < 16; ++i) { a0[i] *= alpha; a1[i] *= alpha; }

      // P B-frag, chunk c: lane (q,hi) needs keys 16c+8hi+e, e=0..7.
#pragma unroll
      for (int c = 0; c < 4; ++c) {
        const int b0 = (c & 1) * 8 + (c >> 1) * 16;   // base(2c); base(2c+1)=b0+4
        const uint32_t P0  = cvtpk(tv[b0 + 0], tv[b0 + 1]);
        const uint32_t P0b = cvtpk(tv[b0 + 2], tv[b0 + 3]);
        const uint32_t P1  = cvtpk(tv[b0 + 4], tv[b0 + 5]);
        const uint32_t P1b = cvtpk(tv[b0 + 6], tv[b0 + 7]);
        const uint32_t sP0  = (uint32_t)__shfl_xor((int)P0, 32);
        const uint32_t sP0b = (uint32_t)__shfl_xor((int)P0b, 32);
        const uint32_t sP1  = (uint32_t)__shfl_xor((int)P1, 32);
        const uint32_t sP1b = (uint32_t)__shfl_xor((int)P1b, 32);
        u32x4 pw;
        pw[0] = hi ? sP1  : P0;
        pw[1] = hi ? sP1b : P0b;
        pw[2] = hi ? P1   : sP0;
        pw[3] = hi ? P1b  : sP0b;
        const bf16x8 pf = __builtin_bit_cast(bf16x8, pw);
        a0 = __builtin_amdgcn_mfma_f32_32x32x16_bf16(V[0][c], pf, a0, 0, 0, 0);
        a1 = __builtin_amdgcn_mfma_f32_32x32x16_bf16(V[1][c], pf, a1, 0, 0, 0);
      }
    };

    bf16x8 kA[2][4], vA[2][4], kB[2][4], vB[2][4];
    prefetch(kA, vA, 0);
    int it = 0;
    for (; it + 1 < niter; it += 2) {
      prefetch(kB, vB, (it + 1) * 64);
      compute(kA, vA, it * 64);
      if (it + 2 < niter) prefetch(kA, vA, (it + 2) * 64);
      compute(kB, vB, (it + 1) * 64);
    }
    if (it < niter) compute(kA, vA, it * 64);

    // epilogue: acc col=q=l31, row=d=(reg&3)+8*(reg>>2)+4hi (+32*dblk)
    const float linv = 1.f / l;
    const size_t rowoff = ((size_t)(b * SEQN + qg)) * DMOD + h * DHEAD;
#pragma unroll
    for (int dblk = 0; dblk < 2; ++dblk) {
      const f32x16& av = dblk ? a1 : a0;
#pragma unroll
      for (int rg = 0; rg < 4; ++rg) {
        const int d0 = dblk * 32 + rg * 8 + 4 * hi;
        bf16x4 ov = { (bf16)(av[rg * 4 + 0] * linv), (bf16)(av[rg * 4 + 1] * linv),
                      (bf16)(av[rg * 4 + 2] * linv), (bf16)(av[rg * 4 + 3] * linv) };
        *(bf16x4*)(AO + rowoff + d0) = ov;
      }
    }
  };

  run_phase(p, wave);
  run_phase(15 - p, 3 - wave);
}

// ---------------------------------------------------------------- out gemm
__global__ __launch_bounds__(256) void gemm_out(
    const bf16* __restrict__ AO, const bf16* __restrict__ Wob,
    const float* __restrict__ bo, float* __restrict__ out)
{
  __shared__ bf16 sA[3][128 * 32];
  __shared__ bf16 sB[3][128 * 32];

  const int t = threadIdx.x;
  const int lane = t & 63, l15 = lane & 15, g = lane >> 4;
  const int wave = t >> 6, wm = wave >> 1, wn = wave & 1;
  const int tileM = blockIdx.y * 128, tileN = blockIdx.x * 128;

  f32x4 acc[4][4] = {};

  const bf16* gA = AO + (size_t)(tileM + (t >> 2)) * DMOD + (t & 3) * 8;
  const bf16* gB = Wob + (size_t)(tileN + (t >> 2)) * DMOD + (t & 3) * 8;

  auto stage = [&](int buf, int k0) {
    gload_lds16(gA + k0, &sA[buf][t * 8]);
    gload_lds16(gA + k0 + 64 * DMOD, &sA[buf][2048 + t * 8]);
    gload_lds16(gB + k0, &sB[buf][t * 8]);
    gload_lds16(gB + k0 + 64 * DMOD, &sB[buf][2048 + t * 8]);
  };

  stage(0, 0);
  stage(1, 32);

  const int NS = DMOD / 32;
  int cur = 0;
  for (int s = 0; s < NS; ++s) {
    if (s + 2 < NS) {
      int pf = cur + 2; if (pf >= 3) pf -= 3;
      stage(pf, (s + 2) * 32);
      asm volatile("s_waitcnt vmcnt(8)" ::: "memory");
    } else if (s + 1 < NS) {
      asm volatile("s_waitcnt vmcnt(4)" ::: "memory");
    } else {
      asm volatile("s_waitcnt vmcnt(0)" ::: "memory");
    }
    __builtin_amdgcn_s_barrier();
    asm volatile("" ::: "memory");

    const bf16* cA = sA[cur];
    const bf16* cB = sB[cur];
    bf16x8 af[4], bfr[4];
#pragma unroll
    for (int i = 0; i < 4; ++i)
      af[i] = *(const bf16x8*)(cA + (wm * 64 + i * 16 + l15) * 32 + g * 8);
#pragma unroll
    for (int j = 0; j < 4; ++j)
      bfr[j] = *(const bf16x8*)(cB + (wn * 64 + j * 16 + l15) * 32 + g * 8);
#pragma unroll
    for (int i = 0; i < 4; ++i)
#pragma unroll
      for (int j = 0; j < 4; ++j)
        acc[i][j] = __builtin_amdgcn_mfma_f32_16x16x32_bf16(af[i], bfr[j], acc[i][j], 0, 0, 0);

    asm volatile("" ::: "memory");
    __builtin_amdgcn_s_barrier();
    cur = (cur == 2) ? 0 : cur + 1;
  }

#pragma unroll
  for (int j = 0; j < 4; ++j) {
    const int col = tileN + wn * 64 + j * 16 + l15;
    const float bcol = bo[col];
#pragma unroll
    for (int i = 0; i < 4; ++i)
#pragma unroll
      for (int r = 0; r < 4; ++r) {
        const int row = tileM + wm * 64 + i * 16 + g * 4 + r;
        out[(size_t)row * DMOD + col] = acc[i][j][r] + bcol;
      }
  }
}

// ---------------------------------------------------------------- launch
extern "C" void kernel_launch(void* const* d_in, const int* in_sizes, int n_in,
                              void* d_out, int out_size, void* d_ws, size_t ws_size,
                              hipStream_t stream)
{
  (void)in_sizes; (void)n_in; (void)out_size; (void)ws_size;
  const float* X  = (const float*)d_in[0];
  const float* Wq = (const float*)d_in[1];
  const float* bq = (const float*)d_in[2];
  const float* Wk = (const float*)d_in[3];
  const float* bk = (const float*)d_in[4];
  const float* Wv = (const float*)d_in[5];
  const float* bv = (const float*)d_in[6];
  const float* Wo = (const float*)d_in[7];
  const float* bo = (const float*)d_in[8];

  char* ws = (char*)d_ws;
  float* ctab = (float*)(ws + 0);
  float* stab = (float*)(ws + 262144);
  bf16* Xb  = (bf16*)(ws + 524288);
  bf16* Wqb = (bf16*)(ws + 8912896);
  bf16* Wkb = (bf16*)(ws + 11010048);
  bf16* Wvb = (bf16*)(ws + 13107200);
  bf16* Wob = (bf16*)(ws + 15204352);
  bf16* Qb  = (bf16*)(ws + 17301504);
  bf16* Kb  = (bf16*)(ws + 25690112);
  bf16* Vtb = (bf16*)(ws + 34078720);   // 32*64*2080*2 = 8519680 bytes
  bf16* AO  = (bf16*)(ws + 42598400);

  prep_kernel<<<1024, 256, 0, stream>>>(X, Wq, Wk, Wv, Wo, Xb, Wqb, Wkb, Wvb, Wob, ctab, stab);
  gemm_qkv<<<dim3(8, 32, 3), 256, 0, stream>>>(Xb, Wqb, Wkb, Wvb, bq, bk, bv, ctab, stab, Qb, Kb, Vtb);
  attn_kernel<<<256, 256, 0, stream>>>(Qb, Kb, Vtb, AO);
  gemm_out<<<dim3(8, 32), 256, 0, stream>>>(AO, Wob, bo, (float*)d_out);
}